// Round 8
// baseline (741.223 us; speedup 1.0000x reference)
//
#include <hip/hip_runtime.h>
#include <math.h>

#define B_   4
#define S_   512
#define DH   1600
#define NH   50
#define PH   32
#define NREL 100
#define MROWS (B_ * S_)          // 2048

typedef _Float16 f16x8 __attribute__((ext_vector_type(8)));
typedef float  floatx4 __attribute__((ext_vector_type(4)));

__device__ __forceinline__ float gelu_f(float x) {
    return 0.5f * x * (1.0f + erff(x * 0.70710678118654752f));
}

__device__ __forceinline__ unsigned short f2h_u(float f) {
    _Float16 h = (_Float16)f;
    return __builtin_bit_cast(unsigned short, h);
}

// ---------------------------------------------------------------------------
// fcast: flat fp32 -> f16
// ---------------------------------------------------------------------------
__global__ __launch_bounds__(256)
void fcast_k(const float* __restrict__ in, unsigned short* __restrict__ out, int n4)
{
    int i = blockIdx.x * 256 + threadIdx.x;
    if (i < n4) {
        float4 v = *(const float4*)&in[i * 4];
        ushort4 o = { f2h_u(v.x), f2h_u(v.y), f2h_u(v.z), f2h_u(v.w) };
        *(ushort4*)&out[i * 4] = o;
    }
}

// ---------------------------------------------------------------------------
// wcast: W[K][N] fp32 -> Wt[N][K] f16, 6 weights via blockIdx.z.
// ---------------------------------------------------------------------------
__global__ __launch_bounds__(256)
void wcast_k(const float* __restrict__ W0, const float* __restrict__ W1,
             const float* __restrict__ W2, const float* __restrict__ W3,
             const float* __restrict__ W4, const float* __restrict__ W5,
             unsigned short* __restrict__ T)
{
    const int z = blockIdx.z;
    const float* W = (z==0)?W0:(z==1)?W1:(z==2)?W2:(z==3)?W3:(z==4)?W4:W5;
    unsigned short* out = T + (size_t)z * DH * DH;

    __shared__ float tile[32][33];
    const int t = threadIdx.x;
    const int n0 = blockIdx.x * 32, k0 = blockIdx.y * 32;
    const int r = t >> 3, c4 = (t & 7) * 4;

    float4 v = *(const float4*)&W[(size_t)(k0 + r) * DH + n0 + c4];
    tile[r][c4 + 0] = v.x; tile[r][c4 + 1] = v.y;
    tile[r][c4 + 2] = v.z; tile[r][c4 + 3] = v.w;
    __syncthreads();

    ushort4 o = { f2h_u(tile[c4 + 0][r]), f2h_u(tile[c4 + 1][r]),
                  f2h_u(tile[c4 + 2][r]), f2h_u(tile[c4 + 3][r]) };
    *(ushort4*)&out[(size_t)(n0 + r) * DH + k0 + c4] = o;
}

// ---------------------------------------------------------------------------
// f16 MFMA GEMM: C = A @ Wt^T + bias (Wt = [N][K] f16). BK=64 (R5-verified).
// 128x64 tile. Used for the QKV GEMM (grid 25x16x3 = 1200 blocks).
// ---------------------------------------------------------------------------
#define BM 128
#define BN 64
#define BK 64
#define LDA 72

template<bool GELU, bool WF32, bool WF16>
__global__ __launch_bounds__(256)
void gemm_f16_k(const unsigned short* __restrict__ Ab,
                const unsigned short* __restrict__ Bt0,
                const unsigned short* __restrict__ Bt1,
                const unsigned short* __restrict__ Bt2,
                const float* __restrict__ bi0, const float* __restrict__ bi1,
                const float* __restrict__ bi2,
                float* __restrict__ Cf0, float* __restrict__ Cf1, float* __restrict__ Cf2,
                unsigned short* __restrict__ Ch0, unsigned short* __restrict__ Ch1,
                unsigned short* __restrict__ Ch2)
{
    const int z = blockIdx.z;
    const unsigned short* Bt = (z==0)?Bt0:(z==1)?Bt1:Bt2;
    const float* bi = (z==0)?bi0:(z==1)?bi1:bi2;
    float* Cf = (z==0)?Cf0:(z==1)?Cf1:Cf2;
    unsigned short* Ch = (z==0)?Ch0:(z==1)?Ch1:Ch2;

    __shared__ __align__(16) unsigned short As[BM * LDA];  // 18432 B
    __shared__ __align__(16) unsigned short Bs[BN * LDA];  //  9216 B

    const int tid = threadIdx.x;
    const int lane = tid & 63, w = tid >> 6;
    const int bm = blockIdx.y * BM, bn = blockIdx.x * BN;
    const int wm = (w >> 1) * 64, wn = (w & 1) * 32;

    const int sr = tid >> 3;          // 0..31
    const int sg = (tid & 7) * 8;     // 0,8,..,56
    const size_t a0 = (size_t)(bm + sr) * DH + sg;
    const size_t b0 = (size_t)(bn + sr) * DH + sg;
    const int al = sr * LDA + sg;

    const int fl_m = lane & 15, fl_g = (lane >> 4) * 8;

    floatx4 acc[4][2] = {};

    for (int k0 = 0; k0 < DH; k0 += BK) {
        uint4 av0 = *(const uint4*)&Ab[a0 + (size_t)  0 * DH + k0];
        uint4 av1 = *(const uint4*)&Ab[a0 + (size_t) 32 * DH + k0];
        uint4 av2 = *(const uint4*)&Ab[a0 + (size_t) 64 * DH + k0];
        uint4 av3 = *(const uint4*)&Ab[a0 + (size_t) 96 * DH + k0];
        uint4 bv0 = *(const uint4*)&Bt[b0 + (size_t)  0 * DH + k0];
        uint4 bv1 = *(const uint4*)&Bt[b0 + (size_t) 32 * DH + k0];
        __syncthreads();
        *(uint4*)&As[al +  0 * LDA] = av0;
        *(uint4*)&As[al + 32 * LDA] = av1;
        *(uint4*)&As[al + 64 * LDA] = av2;
        *(uint4*)&As[al + 96 * LDA] = av3;
        *(uint4*)&Bs[al +  0 * LDA] = bv0;
        *(uint4*)&Bs[al + 32 * LDA] = bv1;
        __syncthreads();

        f16x8 af[2][4], bf[2][2];
        #pragma unroll
        for (int kk = 0; kk < 2; kk++) {
            #pragma unroll
            for (int mt = 0; mt < 4; mt++)
                af[kk][mt] = *(const f16x8*)&As[(wm + mt * 16 + fl_m) * LDA + kk * 32 + fl_g];
            #pragma unroll
            for (int nt = 0; nt < 2; nt++)
                bf[kk][nt] = *(const f16x8*)&Bs[(wn + nt * 16 + fl_m) * LDA + kk * 32 + fl_g];
        }

        #pragma unroll
        for (int kk = 0; kk < 2; kk++)
            #pragma unroll
            for (int mt = 0; mt < 4; mt++)
                #pragma unroll
                for (int nt = 0; nt < 2; nt++)
                    acc[mt][nt] = __builtin_amdgcn_mfma_f32_16x16x32_f16(
                        af[kk][mt], bf[kk][nt], acc[mt][nt], 0, 0, 0);
    }

    const int row_q = (lane >> 4) * 4;
    #pragma unroll
    for (int mt = 0; mt < 4; mt++) {
        #pragma unroll
        for (int nt = 0; nt < 2; nt++) {
            const int col = bn + wn + nt * 16 + fl_m;
            const float bias = bi[col];
            #pragma unroll
            for (int r = 0; r < 4; r++) {
                const int row = bm + wm + mt * 16 + row_q + r;
                float v = acc[mt][nt][r] + bias;
                if (GELU) v = gelu_f(v);
                if (WF32) Cf[(size_t)row * DH + col] = v;
                if (WF16) Ch[(size_t)row * DH + col] = f2h_u(v);
            }
        }
    }
}

// ---------------------------------------------------------------------------
// gemm64: same verified structure, 64x64 tile. For the single GEMMs
// (Wo/W1/W2): grid 25x32 = 800 blocks (vs 400 at 128-tile) -> better CU
// balance on the 256-CU chip. Same staging pattern (2 A insts, 2 B insts),
// same fragment/C-write layout with wm=(w>>1)*32, mt<2.
// ---------------------------------------------------------------------------
template<bool GELU, bool WF32, bool WF16>
__global__ __launch_bounds__(256)
void gemm64_k(const unsigned short* __restrict__ Ab,
              const unsigned short* __restrict__ Bt,
              const float* __restrict__ bi,
              float* __restrict__ Cf, unsigned short* __restrict__ Ch)
{
    __shared__ __align__(16) unsigned short As[64 * LDA];  // 9216 B
    __shared__ __align__(16) unsigned short Bs[64 * LDA];  // 9216 B

    const int tid = threadIdx.x;
    const int lane = tid & 63, w = tid >> 6;
    const int bm = blockIdx.y * 64, bn = blockIdx.x * 64;
    const int wm = (w >> 1) * 32, wn = (w & 1) * 32;

    const int sr = tid >> 3;          // 0..31
    const int sg = (tid & 7) * 8;     // 0,8,..,56
    const size_t a0 = (size_t)(bm + sr) * DH + sg;
    const size_t b0 = (size_t)(bn + sr) * DH + sg;
    const int al = sr * LDA + sg;

    const int fl_m = lane & 15, fl_g = (lane >> 4) * 8;

    floatx4 acc[2][2] = {};

    for (int k0 = 0; k0 < DH; k0 += BK) {
        uint4 av0 = *(const uint4*)&Ab[a0 + (size_t)  0 * DH + k0];
        uint4 av1 = *(const uint4*)&Ab[a0 + (size_t) 32 * DH + k0];
        uint4 bv0 = *(const uint4*)&Bt[b0 + (size_t)  0 * DH + k0];
        uint4 bv1 = *(const uint4*)&Bt[b0 + (size_t) 32 * DH + k0];
        __syncthreads();
        *(uint4*)&As[al +  0 * LDA] = av0;
        *(uint4*)&As[al + 32 * LDA] = av1;
        *(uint4*)&Bs[al +  0 * LDA] = bv0;
        *(uint4*)&Bs[al + 32 * LDA] = bv1;
        __syncthreads();

        f16x8 af[2][2], bf[2][2];
        #pragma unroll
        for (int kk = 0; kk < 2; kk++) {
            #pragma unroll
            for (int mt = 0; mt < 2; mt++)
                af[kk][mt] = *(const f16x8*)&As[(wm + mt * 16 + fl_m) * LDA + kk * 32 + fl_g];
            #pragma unroll
            for (int nt = 0; nt < 2; nt++)
                bf[kk][nt] = *(const f16x8*)&Bs[(wn + nt * 16 + fl_m) * LDA + kk * 32 + fl_g];
        }

        #pragma unroll
        for (int kk = 0; kk < 2; kk++)
            #pragma unroll
            for (int mt = 0; mt < 2; mt++)
                #pragma unroll
                for (int nt = 0; nt < 2; nt++)
                    acc[mt][nt] = __builtin_amdgcn_mfma_f32_16x16x32_f16(
                        af[kk][mt], bf[kk][nt], acc[mt][nt], 0, 0, 0);
    }

    const int row_q = (lane >> 4) * 4;
    #pragma unroll
    for (int mt = 0; mt < 2; mt++) {
        #pragma unroll
        for (int nt = 0; nt < 2; nt++) {
            const int col = bn + wn + nt * 16 + fl_m;
            const float bias = bi[col];
            #pragma unroll
            for (int r = 0; r < 4; r++) {
                const int row = bm + wm + mt * 16 + row_q + r;
                float v = acc[mt][nt][r] + bias;
                if (GELU) v = gelu_f(v);
                if (WF32) Cf[(size_t)row * DH + col] = v;
                if (WF16) Ch[(size_t)row * DH + col] = f2h_u(v);
            }
        }
    }
}

// ---------------------------------------------------------------------------
// MFMA relation-aware attention — VERBATIM R0 baseline (passed @467 µs).
// FROZEN: every restructure attempt (R1-R4, R6, R7) died with an
// unwritten-output signature regardless of semantics. Do not modify.
// ---------------------------------------------------------------------------
__global__ __launch_bounds__(256, 1)
void attn_k(const unsigned short* __restrict__ Qg,
            const unsigned short* __restrict__ Kg,
            const unsigned short* __restrict__ Vg,
            const float* __restrict__ relk, const float* __restrict__ relv,
            const int* __restrict__ RM, unsigned short* __restrict__ CTX)
{
    __shared__ union {
        unsigned short Kb[512 * 40];   // 40960 B  (score phase)
        unsigned short VT[32 * 520];   // 33280 B  (PV phase)
        float          qf[64 * 36];    // 36864 B  (qrel phase)
    } big;
    __shared__ unsigned char rmb[64 * 516];    // 33024 B
    __shared__ float qrel[64 * 101];           // 25856 B
    __shared__ float wsum[64 * 101];           // 25856 B
    __shared__ float relb[NREL * 36];          // 14400 B (rel_k then rel_v)
    __shared__ unsigned short Pb[4][2][16 * 40]; // 10240 B

    const int tid = threadIdx.x;
    const int w = tid >> 6, lane = tid & 63;
    const int cl = lane & 15, quad = lane >> 4;
    const int b = blockIdx.z, h = blockIdx.y, q0 = blockIdx.x * 64;
    const float scale = 0.17677669529663689f;   // 1/sqrt(32)

    // ---------------- P0 ----------------
    for (int i = tid; i < 64 * 101; i += 256) wsum[i] = 0.f;
    {   // q tile -> fp32 LDS [64][36]
        int row = tid >> 2, g = tid & 3;
        uint4 qv = *(const uint4*)&Qg[(size_t)(b * S_ + q0 + row) * DH + h * PH + g * 8];
        f16x8 qh = __builtin_bit_cast(f16x8, qv);
        #pragma unroll
        for (int j = 0; j < 8; j++) big.qf[row * 36 + g * 8 + j] = (float)qh[j];
    }
    for (int i = tid; i < NREL * 8; i += 256) {   // rel_k fp32 [100][36]
        int r = i >> 3, dg = i & 7;
        *(float4*)&relb[r * 36 + dg * 4] = *(const float4*)&relk[r * PH + dg * 4];
    }
    #pragma unroll
    for (int it = 0; it < 32; it++) {   // rm -> u8 [64][516]
        int idx = it * 256 + tid;
        int key4 = idx & 127, ql = idx >> 7;
        int4 rv = *(const int4*)&RM[(size_t)(b * S_ + q0 + ql) * S_ + key4 * 4];
        uchar4 o = { (unsigned char)rv.x, (unsigned char)rv.y,
                     (unsigned char)rv.z, (unsigned char)rv.w };
        *(uchar4*)&rmb[ql * 516 + key4 * 4] = o;
    }
    __syncthreads();

    // ---------------- P1: qrel[q][r] ----------------
    {
        const int q = tid >> 2, rsub = tid & 3;
        float qv[PH];
        #pragma unroll
        for (int d = 0; d < PH; d++) qv[d] = big.qf[q * 36 + d];
        for (int i = 0; i < 25; i++) {
            int r = rsub * 25 + i;
            float s = 0.f;
            #pragma unroll
            for (int d = 0; d < PH; d++) s += qv[d] * relb[r * 36 + d];
            qrel[q * 101 + r] = s;
        }
    }
    __syncthreads();

    // ---------------- P2: stage K rows + rel_v ----------------
    #pragma unroll
    for (int it = 0; it < 8; it++) {
        int idx = it * 256 + tid;
        int key = idx >> 2, g = idx & 3;
        uint4 kv = *(const uint4*)&Kg[(size_t)(b * S_ + key) * DH + h * PH + g * 8];
        *(uint4*)&big.Kb[key * 40 + g * 8] = kv;
    }
    for (int i = tid; i < NREL * 8; i += 256) {
        int r = i >> 3, dg = i & 7;
        *(float4*)&relb[r * 36 + dg * 4] = *(const float4*)&relv[r * PH + dg * 4];
    }
    __syncthreads();

    // ---------------- P3: scores + bias + softmax + scatter ----------------
    floatx4 acc[32];
    {
        f16x8 qa = __builtin_bit_cast(f16x8, *(const uint4*)
            &Qg[(size_t)(b * S_ + q0 + w * 16 + cl) * DH + h * PH + quad * 8]);
        #pragma unroll
        for (int t = 0; t < 32; t++) {
            f16x8 kf = *(const f16x8*)&big.Kb[(t * 16 + cl) * 40 + quad * 8];
            acc[t] = __builtin_amdgcn_mfma_f32_16x16x32_f16(qa, kf, (floatx4){}, 0, 0, 0);
        }
        // bias + scale (C layout: col=key=cl+16t, row=q= w*16+quad*4+r)
        #pragma unroll
        for (int t = 0; t < 32; t++) {
            #pragma unroll
            for (int r = 0; r < 4; r++) {
                int ql = w * 16 + quad * 4 + r;
                int rm = rmb[ql * 516 + t * 16 + cl];
                acc[t][r] = (acc[t][r] + qrel[ql * 101 + rm]) * scale;
            }
        }
        // softmax per row (4 rows in parallel, reduce over 32 regs + 16 lanes)
        float mx[4] = {-1e30f, -1e30f, -1e30f, -1e30f};
        #pragma unroll
        for (int t = 0; t < 32; t++)
            #pragma unroll
            for (int r = 0; r < 4; r++) mx[r] = fmaxf(mx[r], acc[t][r]);
        #pragma unroll
        for (int r = 0; r < 4; r++) {
            #pragma unroll
            for (int off = 1; off < 16; off <<= 1)
                mx[r] = fmaxf(mx[r], __shfl_xor(mx[r], off));
        }
        float sm[4] = {};
        #pragma unroll
        for (int t = 0; t < 32; t++)
            #pragma unroll
            for (int r = 0; r < 4; r++) {
                float e = __expf(acc[t][r] - mx[r]);
                acc[t][r] = e; sm[r] += e;
            }
        #pragma unroll
        for (int r = 0; r < 4; r++) {
            #pragma unroll
            for (int off = 1; off < 16; off <<= 1)
                sm[r] += __shfl_xor(sm[r], off);
            sm[r] = 1.0f / sm[r];
        }
        #pragma unroll
        for (int t = 0; t < 32; t++)
            #pragma unroll
            for (int r = 0; r < 4; r++) acc[t][r] *= sm[r];
        // wsum scatter
        #pragma unroll
        for (int t = 0; t < 32; t++) {
            #pragma unroll
            for (int r = 0; r < 4; r++) {
                int ql = w * 16 + quad * 4 + r;
                int rm = rmb[ql * 516 + t * 16 + cl];
                atomicAdd(&wsum[ql * 101 + rm], acc[t][r]);
            }
        }
    }
    __syncthreads();

    // ---------------- P4: stage V^T [32 d][520 keys] ----------------
    #pragma unroll
    for (int it = 0; it < 8; it++) {
        int idx = it * 256 + tid;
        int key = idx >> 2, part = idx & 3;
        uint4 vv = *(const uint4*)&Vg[(size_t)(b * S_ + key) * DH + h * PH + part * 8];
        f16x8 vh = __builtin_bit_cast(f16x8, vv);
        #pragma unroll
        for (int j = 0; j < 8; j++)
            big.VT[(part * 8 + j) * 520 + key] = f2h_u((float)vh[j]) , (void)0;
    }
    __syncthreads();

    // ---------------- P5: PV + ctx_rel + write ----------------
    {
        floatx4 ctx[2] = {};
        #pragma unroll
        for (int c = 0; c < 16; c++) {
            // write P chunk (32 keys) to per-wave buffer, C-layout -> rows
            #pragma unroll
            for (int tt = 0; tt < 2; tt++) {
                #pragma unroll
                for (int r = 0; r < 4; r++)
                    Pb[w][c & 1][(quad * 4 + r) * 40 + tt * 16 + cl] =
                        f2h_u(acc[c * 2 + tt][r]);
            }
            f16x8 pa = *(const f16x8*)&Pb[w][c & 1][cl * 40 + quad * 8];
            #pragma unroll
            for (int nt = 0; nt < 2; nt++) {
                f16x8 vf = *(const f16x8*)&big.VT[(nt * 16 + cl) * 520 + c * 32 + quad * 8];
                ctx[nt] = __builtin_amdgcn_mfma_f32_16x16x32_f16(pa, vf, ctx[nt], 0, 0, 0);
            }
        }
        // ctx_rel = wsum @ rel_v
        for (int r = 0; r < NREL; r++) {
            float rv0 = relb[r * 36 + cl];
            float rv1 = relb[r * 36 + 16 + cl];
            #pragma unroll
            for (int rr = 0; rr < 4; rr++) {
                float ws = wsum[(w * 16 + quad * 4 + rr) * 101 + r];
                ctx[0][rr] += ws * rv0;
                ctx[1][rr] += ws * rv1;
            }
        }
        #pragma unroll
        for (int nt = 0; nt < 2; nt++) {
            #pragma unroll
            for (int rr = 0; rr < 4; rr++) {
                int row = b * S_ + q0 + w * 16 + quad * 4 + rr;
                int col = h * PH + nt * 16 + cl;
                CTX[(size_t)row * DH + col] = f2h_u(ctx[nt][rr]);
            }
        }
    }
}

// ---------------------------------------------------------------------------
extern "C" void kernel_launch(void* const* d_in, const int* in_sizes, int n_in,
                              void* d_out, int out_size, void* d_ws, size_t ws_size,
                              hipStream_t stream)
{
    const float* hidden = (const float*)d_in[0];
    const float* Wq = (const float*)d_in[1];  const float* bq = (const float*)d_in[2];
    const float* Wk = (const float*)d_in[3];  const float* bk = (const float*)d_in[4];
    const float* Wv = (const float*)d_in[5];  const float* bv = (const float*)d_in[6];
    const float* Wo = (const float*)d_in[7];  const float* bo = (const float*)d_in[8];
    const float* relk = (const float*)d_in[9];
    const float* relv = (const float*)d_in[10];
    const float* W1 = (const float*)d_in[11]; const float* b1 = (const float*)d_in[12];
    const float* W2 = (const float*)d_in[13]; const float* b2 = (const float*)d_in[14];
    const int*   RM = (const int*)d_in[15];
    float* out = (float*)d_out;

    const size_t SZ = (size_t)MROWS * DH;          // 3,276,800 elems
    const size_t SZB = SZ * 2;                     // f16 bytes

    char* ws = (char*)d_ws;
    unsigned short* hb   = (unsigned short*)(ws);              // hidden f16
    unsigned short* qf   = (unsigned short*)(ws + SZB);        // q f16
    unsigned short* kf   = (unsigned short*)(ws + 2*SZB);      // k f16
    unsigned short* vf   = (unsigned short*)(ws + 3*SZB);      // v f16
    unsigned short* ctxf = (unsigned short*)(ws + 4*SZB);      // ctx f16
    unsigned short* aof  = (unsigned short*)(ws + 5*SZB);      // attn_out f16
    unsigned short* hff  = (unsigned short*)(ws + 6*SZB);      // ffn hidden f16
    unsigned short* Wt   = (unsigned short*)(ws + 7*SZB);      // 6 x [N][K] f16
    const size_t WSZ = (size_t)DH * DH;
    unsigned short *Wtq = Wt,         *Wtk = Wt + WSZ,   *Wtv = Wt + 2*WSZ,
                   *Wto = Wt + 3*WSZ, *Wt1 = Wt + 4*WSZ, *Wt2 = Wt + 5*WSZ;

    fcast_k<<<dim3((SZ/4 + 255)/256), 256, 0, stream>>>(hidden, hb, (int)(SZ/4));
    wcast_k<<<dim3(DH/32, DH/32, 6), 256, 0, stream>>>(Wq, Wk, Wv, Wo, W1, W2, Wt);

    // QKV (f16 out) — 128-tile, z=3, 1200 blocks
    gemm_f16_k<false, false, true><<<dim3(DH/BN, MROWS/BM, 3), 256, 0, stream>>>(
        hb, Wtq, Wtk, Wtv, bq, bk, bv,
        nullptr, nullptr, nullptr, qf, kf, vf);

    attn_k<<<dim3(S_/64, NH, B_), 256, 0, stream>>>(qf, kf, vf, relk, relv, RM, ctxf);

    // single GEMMs — 64-tile, 800 blocks each (better CU balance than 400)
    // attn_out = ctx @ Wo + bo
    gemm64_k<false, false, true><<<dim3(DH/64, MROWS/64, 1), 256, 0, stream>>>(
        ctxf, Wto, bo, nullptr, aof);

    // h = gelu(attn_out @ W1 + b1)
    gemm64_k<true, false, true><<<dim3(DH/64, MROWS/64, 1), 256, 0, stream>>>(
        aof, Wt1, b1, nullptr, hff);

    // out = h @ W2 + b2  (fp32 out)
    gemm64_k<false, true, false><<<dim3(DH/64, MROWS/64, 1), 256, 0, stream>>>(
        hff, Wt2, b2, out, nullptr);
}

// Round 9
// 723.565 us; speedup vs baseline: 1.0244x; 1.0244x over previous
//
#include <hip/hip_runtime.h>
#include <math.h>

#define B_   4
#define S_   512
#define DH   1600
#define NH   50
#define PH   32
#define NREL 100
#define MROWS (B_ * S_)          // 2048

typedef _Float16 f16x8 __attribute__((ext_vector_type(8)));
typedef float  floatx4 __attribute__((ext_vector_type(4)));

__device__ __forceinline__ float gelu_f(float x) {
    return 0.5f * x * (1.0f + erff(x * 0.70710678118654752f));
}

__device__ __forceinline__ unsigned short f2h_u(float f) {
    _Float16 h = (_Float16)f;
    return __builtin_bit_cast(unsigned short, h);
}

// global -> LDS direct copy, 16 B per lane (gfx950 global_load_lds_dwordx4).
// LDS dest is wave-uniform base + lane*16; global src is per-lane.
typedef const __attribute__((address_space(1))) unsigned int guint;
typedef __attribute__((address_space(3))) unsigned int luint;
__device__ __forceinline__ void gl_lds16(const unsigned short* g, unsigned short* l)
{
    __builtin_amdgcn_global_load_lds((guint*)g, (luint*)l, 16, 0, 0);
}

// ---------------------------------------------------------------------------
// fcast: flat fp32 -> f16
// ---------------------------------------------------------------------------
__global__ __launch_bounds__(256)
void fcast_k(const float* __restrict__ in, unsigned short* __restrict__ out, int n4)
{
    int i = blockIdx.x * 256 + threadIdx.x;
    if (i < n4) {
        float4 v = *(const float4*)&in[i * 4];
        ushort4 o = { f2h_u(v.x), f2h_u(v.y), f2h_u(v.z), f2h_u(v.w) };
        *(ushort4*)&out[i * 4] = o;
    }
}

// ---------------------------------------------------------------------------
// wcast: W[K][N] fp32 -> Wt[N][K] f16, 6 weights via blockIdx.z.
// ---------------------------------------------------------------------------
__global__ __launch_bounds__(256)
void wcast_k(const float* __restrict__ W0, const float* __restrict__ W1,
             const float* __restrict__ W2, const float* __restrict__ W3,
             const float* __restrict__ W4, const float* __restrict__ W5,
             unsigned short* __restrict__ T)
{
    const int z = blockIdx.z;
    const float* W = (z==0)?W0:(z==1)?W1:(z==2)?W2:(z==3)?W3:(z==4)?W4:W5;
    unsigned short* out = T + (size_t)z * DH * DH;

    __shared__ float tile[32][33];
    const int t = threadIdx.x;
    const int n0 = blockIdx.x * 32, k0 = blockIdx.y * 32;
    const int r = t >> 3, c4 = (t & 7) * 4;

    float4 v = *(const float4*)&W[(size_t)(k0 + r) * DH + n0 + c4];
    tile[r][c4 + 0] = v.x; tile[r][c4 + 1] = v.y;
    tile[r][c4 + 2] = v.z; tile[r][c4 + 3] = v.w;
    __syncthreads();

    ushort4 o = { f2h_u(tile[c4 + 0][r]), f2h_u(tile[c4 + 1][r]),
                  f2h_u(tile[c4 + 2][r]), f2h_u(tile[c4 + 3][r]) };
    *(ushort4*)&out[(size_t)(n0 + r) * DH + k0 + c4] = o;
}

// ---------------------------------------------------------------------------
// f16 MFMA GEMM: C = A @ Wt^T + bias (Wt = [N][K] f16). BK=64, 128x64 tile.
// Staging via global_load_lds (16B/lane, linear LDS dest) with XOR-swizzled
// layout (rule #21: linear dest + inverse-swz SOURCE + swz on READ):
//   LDS unit u = row*8 + j  holds  A[row][j ^ (row&7)]  (16B groups)
//   read of logical group G=kk*4+quad uses unit row*8 + (G ^ (fl_m&7))
// Bank spread on ds_read_b128: 8 lanes per 4-bank group (even) = conflict-
// free floor, same as the previous padded LDA=72 layout. MFMA order and
// operand values identical to the R5-verified kernel -> same absmax.
// ---------------------------------------------------------------------------
#define BM 128
#define BN 64
#define BK 64

template<bool GELU, bool WF32, bool WF16>
__global__ __launch_bounds__(256)
void gemm_f16_k(const unsigned short* __restrict__ Ab,
                const unsigned short* __restrict__ Bt0,
                const unsigned short* __restrict__ Bt1,
                const unsigned short* __restrict__ Bt2,
                const float* __restrict__ bi0, const float* __restrict__ bi1,
                const float* __restrict__ bi2,
                float* __restrict__ Cf0, float* __restrict__ Cf1, float* __restrict__ Cf2,
                unsigned short* __restrict__ Ch0, unsigned short* __restrict__ Ch1,
                unsigned short* __restrict__ Ch2)
{
    const int z = blockIdx.z;
    const unsigned short* Bt = (z==0)?Bt0:(z==1)?Bt1:Bt2;
    const float* bi = (z==0)?bi0:(z==1)?bi1:bi2;
    float* Cf = (z==0)?Cf0:(z==1)?Cf1:Cf2;
    unsigned short* Ch = (z==0)?Ch0:(z==1)?Ch1:Ch2;

    __shared__ __align__(16) unsigned short As[BM * BK];  // 16384 B, linear
    __shared__ __align__(16) unsigned short Bs[BN * BK];  //  8192 B, linear

    const int tid = threadIdx.x;
    const int lane = tid & 63, w = tid >> 6;
    const int bm = blockIdx.y * BM, bn = blockIdx.x * BN;
    const int wm = (w >> 1) * 64, wn = (w & 1) * 32;

    // staging geometry: per 64-unit wave chunk, lane covers
    //   row = chunkrow*8 + (lane>>3),  unit j = lane&7,
    //   source 16B-group = j ^ (lane>>3)   (inverse swizzle)
    const int lr8 = lane >> 3;                 // 0..7 == row&7
    const int sgrp = ((lane & 7) ^ lr8) * 8;   // source half offset 0..56

    const int fl_m = lane & 15, quad = lane >> 4;
    const int rs = fl_m & 7;                   // row&7 for fragment rows
    const int g0 = (quad ^ rs) * 8;            // swizzled group (kk=0), halves

    floatx4 acc[4][2] = {};

    for (int k0 = 0; k0 < DH; k0 += BK) {
        __syncthreads();   // prior iteration's ds_reads complete
        #pragma unroll
        for (int c = 0; c < 4; c++) {          // A: 4 chunks/wave
            int rowb = (c * 4 + w) * 8;
            gl_lds16(&Ab[(size_t)(bm + rowb + lr8) * DH + k0 + sgrp],
                     &As[(c * 4 + w) * 512]);
        }
        #pragma unroll
        for (int c = 0; c < 2; c++) {          // B: 2 chunks/wave
            int rowb = (c * 4 + w) * 8;
            gl_lds16(&Bt[(size_t)(bn + rowb + lr8) * DH + k0 + sgrp],
                     &Bs[(c * 4 + w) * 512]);
        }
        __syncthreads();   // drains vmcnt -> LDS populated

        f16x8 af[2][4], bf[2][2];
        #pragma unroll
        for (int kk = 0; kk < 2; kk++) {
            const int gg = g0 ^ (kk * 32);     // (quad^rs ^ kk*4)*8 halves
            #pragma unroll
            for (int mt = 0; mt < 4; mt++)
                af[kk][mt] = *(const f16x8*)&As[(wm + mt * 16 + fl_m) * 64 + gg];
            #pragma unroll
            for (int nt = 0; nt < 2; nt++)
                bf[kk][nt] = *(const f16x8*)&Bs[(wn + nt * 16 + fl_m) * 64 + gg];
        }

        #pragma unroll
        for (int kk = 0; kk < 2; kk++)
            #pragma unroll
            for (int mt = 0; mt < 4; mt++)
                #pragma unroll
                for (int nt = 0; nt < 2; nt++)
                    acc[mt][nt] = __builtin_amdgcn_mfma_f32_16x16x32_f16(
                        af[kk][mt], bf[kk][nt], acc[mt][nt], 0, 0, 0);
    }

    const int row_q = (lane >> 4) * 4;
    #pragma unroll
    for (int mt = 0; mt < 4; mt++) {
        #pragma unroll
        for (int nt = 0; nt < 2; nt++) {
            const int col = bn + wn + nt * 16 + fl_m;
            const float bias = bi[col];
            #pragma unroll
            for (int r = 0; r < 4; r++) {
                const int row = bm + wm + mt * 16 + row_q + r;
                float v = acc[mt][nt][r] + bias;
                if (GELU) v = gelu_f(v);
                if (WF32) Cf[(size_t)row * DH + col] = v;
                if (WF16) Ch[(size_t)row * DH + col] = f2h_u(v);
            }
        }
    }
}

// ---------------------------------------------------------------------------
// MFMA relation-aware attention — VERBATIM R0 baseline (passed @467 µs).
// FROZEN: every restructure attempt (R1-R4, R6, R7) died with an
// unwritten-output signature regardless of semantics. Do not modify.
// ---------------------------------------------------------------------------
__global__ __launch_bounds__(256, 1)
void attn_k(const unsigned short* __restrict__ Qg,
            const unsigned short* __restrict__ Kg,
            const unsigned short* __restrict__ Vg,
            const float* __restrict__ relk, const float* __restrict__ relv,
            const int* __restrict__ RM, unsigned short* __restrict__ CTX)
{
    __shared__ union {
        unsigned short Kb[512 * 40];   // 40960 B  (score phase)
        unsigned short VT[32 * 520];   // 33280 B  (PV phase)
        float          qf[64 * 36];    // 36864 B  (qrel phase)
    } big;
    __shared__ unsigned char rmb[64 * 516];    // 33024 B
    __shared__ float qrel[64 * 101];           // 25856 B
    __shared__ float wsum[64 * 101];           // 25856 B
    __shared__ float relb[NREL * 36];          // 14400 B (rel_k then rel_v)
    __shared__ unsigned short Pb[4][2][16 * 40]; // 10240 B

    const int tid = threadIdx.x;
    const int w = tid >> 6, lane = tid & 63;
    const int cl = lane & 15, quad = lane >> 4;
    const int b = blockIdx.z, h = blockIdx.y, q0 = blockIdx.x * 64;
    const float scale = 0.17677669529663689f;   // 1/sqrt(32)

    // ---------------- P0 ----------------
    for (int i = tid; i < 64 * 101; i += 256) wsum[i] = 0.f;
    {   // q tile -> fp32 LDS [64][36]
        int row = tid >> 2, g = tid & 3;
        uint4 qv = *(const uint4*)&Qg[(size_t)(b * S_ + q0 + row) * DH + h * PH + g * 8];
        f16x8 qh = __builtin_bit_cast(f16x8, qv);
        #pragma unroll
        for (int j = 0; j < 8; j++) big.qf[row * 36 + g * 8 + j] = (float)qh[j];
    }
    for (int i = tid; i < NREL * 8; i += 256) {   // rel_k fp32 [100][36]
        int r = i >> 3, dg = i & 7;
        *(float4*)&relb[r * 36 + dg * 4] = *(const float4*)&relk[r * PH + dg * 4];
    }
    #pragma unroll
    for (int it = 0; it < 32; it++) {   // rm -> u8 [64][516]
        int idx = it * 256 + tid;
        int key4 = idx & 127, ql = idx >> 7;
        int4 rv = *(const int4*)&RM[(size_t)(b * S_ + q0 + ql) * S_ + key4 * 4];
        uchar4 o = { (unsigned char)rv.x, (unsigned char)rv.y,
                     (unsigned char)rv.z, (unsigned char)rv.w };
        *(uchar4*)&rmb[ql * 516 + key4 * 4] = o;
    }
    __syncthreads();

    // ---------------- P1: qrel[q][r] ----------------
    {
        const int q = tid >> 2, rsub = tid & 3;
        float qv[PH];
        #pragma unroll
        for (int d = 0; d < PH; d++) qv[d] = big.qf[q * 36 + d];
        for (int i = 0; i < 25; i++) {
            int r = rsub * 25 + i;
            float s = 0.f;
            #pragma unroll
            for (int d = 0; d < PH; d++) s += qv[d] * relb[r * 36 + d];
            qrel[q * 101 + r] = s;
        }
    }
    __syncthreads();

    // ---------------- P2: stage K rows + rel_v ----------------
    #pragma unroll
    for (int it = 0; it < 8; it++) {
        int idx = it * 256 + tid;
        int key = idx >> 2, g = idx & 3;
        uint4 kv = *(const uint4*)&Kg[(size_t)(b * S_ + key) * DH + h * PH + g * 8];
        *(uint4*)&big.Kb[key * 40 + g * 8] = kv;
    }
    for (int i = tid; i < NREL * 8; i += 256) {
        int r = i >> 3, dg = i & 7;
        *(float4*)&relb[r * 36 + dg * 4] = *(const float4*)&relv[r * PH + dg * 4];
    }
    __syncthreads();

    // ---------------- P3: scores + bias + softmax + scatter ----------------
    floatx4 acc[32];
    {
        f16x8 qa = __builtin_bit_cast(f16x8, *(const uint4*)
            &Qg[(size_t)(b * S_ + q0 + w * 16 + cl) * DH + h * PH + quad * 8]);
        #pragma unroll
        for (int t = 0; t < 32; t++) {
            f16x8 kf = *(const f16x8*)&big.Kb[(t * 16 + cl) * 40 + quad * 8];
            acc[t] = __builtin_amdgcn_mfma_f32_16x16x32_f16(qa, kf, (floatx4){}, 0, 0, 0);
        }
        // bias + scale (C layout: col=key=cl+16t, row=q= w*16+quad*4+r)
        #pragma unroll
        for (int t = 0; t < 32; t++) {
            #pragma unroll
            for (int r = 0; r < 4; r++) {
                int ql = w * 16 + quad * 4 + r;
                int rm = rmb[ql * 516 + t * 16 + cl];
                acc[t][r] = (acc[t][r] + qrel[ql * 101 + rm]) * scale;
            }
        }
        // softmax per row (4 rows in parallel, reduce over 32 regs + 16 lanes)
        float mx[4] = {-1e30f, -1e30f, -1e30f, -1e30f};
        #pragma unroll
        for (int t = 0; t < 32; t++)
            #pragma unroll
            for (int r = 0; r < 4; r++) mx[r] = fmaxf(mx[r], acc[t][r]);
        #pragma unroll
        for (int r = 0; r < 4; r++) {
            #pragma unroll
            for (int off = 1; off < 16; off <<= 1)
                mx[r] = fmaxf(mx[r], __shfl_xor(mx[r], off));
        }
        float sm[4] = {};
        #pragma unroll
        for (int t = 0; t < 32; t++)
            #pragma unroll
            for (int r = 0; r < 4; r++) {
                float e = __expf(acc[t][r] - mx[r]);
                acc[t][r] = e; sm[r] += e;
            }
        #pragma unroll
        for (int r = 0; r < 4; r++) {
            #pragma unroll
            for (int off = 1; off < 16; off <<= 1)
                sm[r] += __shfl_xor(sm[r], off);
            sm[r] = 1.0f / sm[r];
        }
        #pragma unroll
        for (int t = 0; t < 32; t++)
            #pragma unroll
            for (int r = 0; r < 4; r++) acc[t][r] *= sm[r];
        // wsum scatter
        #pragma unroll
        for (int t = 0; t < 32; t++) {
            #pragma unroll
            for (int r = 0; r < 4; r++) {
                int ql = w * 16 + quad * 4 + r;
                int rm = rmb[ql * 516 + t * 16 + cl];
                atomicAdd(&wsum[ql * 101 + rm], acc[t][r]);
            }
        }
    }
    __syncthreads();

    // ---------------- P4: stage V^T [32 d][520 keys] ----------------
    #pragma unroll
    for (int it = 0; it < 8; it++) {
        int idx = it * 256 + tid;
        int key = idx >> 2, part = idx & 3;
        uint4 vv = *(const uint4*)&Vg[(size_t)(b * S_ + key) * DH + h * PH + part * 8];
        f16x8 vh = __builtin_bit_cast(f16x8, vv);
        #pragma unroll
        for (int j = 0; j < 8; j++)
            big.VT[(part * 8 + j) * 520 + key] = f2h_u((float)vh[j]) , (void)0;
    }
    __syncthreads();

    // ---------------- P5: PV + ctx_rel + write ----------------
    {
        floatx4 ctx[2] = {};
        #pragma unroll
        for (int c = 0; c < 16; c++) {
            // write P chunk (32 keys) to per-wave buffer, C-layout -> rows
            #pragma unroll
            for (int tt = 0; tt < 2; tt++) {
                #pragma unroll
                for (int r = 0; r < 4; r++)
                    Pb[w][c & 1][(quad * 4 + r) * 40 + tt * 16 + cl] =
                        f2h_u(acc[c * 2 + tt][r]);
            }
            f16x8 pa = *(const f16x8*)&Pb[w][c & 1][cl * 40 + quad * 8];
            #pragma unroll
            for (int nt = 0; nt < 2; nt++) {
                f16x8 vf = *(const f16x8*)&big.VT[(nt * 16 + cl) * 520 + c * 32 + quad * 8];
                ctx[nt] = __builtin_amdgcn_mfma_f32_16x16x32_f16(pa, vf, ctx[nt], 0, 0, 0);
            }
        }
        // ctx_rel = wsum @ rel_v
        for (int r = 0; r < NREL; r++) {
            float rv0 = relb[r * 36 + cl];
            float rv1 = relb[r * 36 + 16 + cl];
            #pragma unroll
            for (int rr = 0; rr < 4; rr++) {
                float ws = wsum[(w * 16 + quad * 4 + rr) * 101 + r];
                ctx[0][rr] += ws * rv0;
                ctx[1][rr] += ws * rv1;
            }
        }
        #pragma unroll
        for (int nt = 0; nt < 2; nt++) {
            #pragma unroll
            for (int rr = 0; rr < 4; rr++) {
                int row = b * S_ + q0 + w * 16 + quad * 4 + rr;
                int col = h * PH + nt * 16 + cl;
                CTX[(size_t)row * DH + col] = f2h_u(ctx[nt][rr]);
            }
        }
    }
}

// ---------------------------------------------------------------------------
extern "C" void kernel_launch(void* const* d_in, const int* in_sizes, int n_in,
                              void* d_out, int out_size, void* d_ws, size_t ws_size,
                              hipStream_t stream)
{
    const float* hidden = (const float*)d_in[0];
    const float* Wq = (const float*)d_in[1];  const float* bq = (const float*)d_in[2];
    const float* Wk = (const float*)d_in[3];  const float* bk = (const float*)d_in[4];
    const float* Wv = (const float*)d_in[5];  const float* bv = (const float*)d_in[6];
    const float* Wo = (const float*)d_in[7];  const float* bo = (const float*)d_in[8];
    const float* relk = (const float*)d_in[9];
    const float* relv = (const float*)d_in[10];
    const float* W1 = (const float*)d_in[11]; const float* b1 = (const float*)d_in[12];
    const float* W2 = (const float*)d_in[13]; const float* b2 = (const float*)d_in[14];
    const int*   RM = (const int*)d_in[15];
    float* out = (float*)d_out;

    const size_t SZ = (size_t)MROWS * DH;          // 3,276,800 elems
    const size_t SZB = SZ * 2;                     // f16 bytes

    char* ws = (char*)d_ws;
    unsigned short* hb   = (unsigned short*)(ws);              // hidden f16
    unsigned short* qf   = (unsigned short*)(ws + SZB);        // q f16
    unsigned short* kf   = (unsigned short*)(ws + 2*SZB);      // k f16
    unsigned short* vf   = (unsigned short*)(ws + 3*SZB);      // v f16
    unsigned short* ctxf = (unsigned short*)(ws + 4*SZB);      // ctx f16
    unsigned short* aof  = (unsigned short*)(ws + 5*SZB);      // attn_out f16
    unsigned short* hff  = (unsigned short*)(ws + 6*SZB);      // ffn hidden f16
    unsigned short* Wt   = (unsigned short*)(ws + 7*SZB);      // 6 x [N][K] f16
    const size_t WSZ = (size_t)DH * DH;
    unsigned short *Wtq = Wt,         *Wtk = Wt + WSZ,   *Wtv = Wt + 2*WSZ,
                   *Wto = Wt + 3*WSZ, *Wt1 = Wt + 4*WSZ, *Wt2 = Wt + 5*WSZ;

    fcast_k<<<dim3((SZ/4 + 255)/256), 256, 0, stream>>>(hidden, hb, (int)(SZ/4));
    wcast_k<<<dim3(DH/32, DH/32, 6), 256, 0, stream>>>(Wq, Wk, Wv, Wo, W1, W2, Wt);

    // QKV (f16 out)
    gemm_f16_k<false, false, true><<<dim3(DH/BN, MROWS/BM, 3), 256, 0, stream>>>(
        hb, Wtq, Wtk, Wtv, bq, bk, bv,
        nullptr, nullptr, nullptr, qf, kf, vf);

    attn_k<<<dim3(S_/64, NH, B_), 256, 0, stream>>>(qf, kf, vf, relk, relv, RM, ctxf);

    // attn_out = ctx @ Wo + bo
    gemm_f16_k<false, false, true><<<dim3(DH/BN, MROWS/BM, 1), 256, 0, stream>>>(
        ctxf, Wto, Wto, Wto, bo, bo, bo,
        nullptr, nullptr, nullptr, aof, aof, aof);

    // h = gelu(attn_out @ W1 + b1)
    gemm_f16_k<true, false, true><<<dim3(DH/BN, MROWS/BM, 1), 256, 0, stream>>>(
        aof, Wt1, Wt1, Wt1, b1, b1, b1,
        nullptr, nullptr, nullptr, hff, hff, hff);

    // out = h @ W2 + b2  (fp32 out)
    gemm_f16_k<false, true, false><<<dim3(DH/BN, MROWS/BM, 1), 256, 0, stream>>>(
        hff, Wt2, Wt2, Wt2, b2, b2, b2,
        out, out, out, nullptr, nullptr, nullptr);
}

// Round 10
// 716.980 us; speedup vs baseline: 1.0338x; 1.0092x over previous
//
#include <hip/hip_runtime.h>
#include <math.h>

#define B_   4
#define S_   512
#define DH   1600
#define NH   50
#define PH   32
#define NREL 100
#define MROWS (B_ * S_)          // 2048

typedef _Float16 f16x8 __attribute__((ext_vector_type(8)));
typedef float  floatx4 __attribute__((ext_vector_type(4)));

__device__ __forceinline__ float gelu_f(float x) {
    return 0.5f * x * (1.0f + erff(x * 0.70710678118654752f));
}

__device__ __forceinline__ unsigned short f2h_u(float f) {
    _Float16 h = (_Float16)f;
    return __builtin_bit_cast(unsigned short, h);
}

// global -> LDS direct copy, 16 B per lane (gfx950 global_load_lds_dwordx4).
typedef const __attribute__((address_space(1))) unsigned int guint;
typedef __attribute__((address_space(3))) unsigned int luint;
__device__ __forceinline__ void gl_lds16(const unsigned short* g, unsigned short* l)
{
    __builtin_amdgcn_global_load_lds((guint*)g, (luint*)l, 16, 0, 0);
}

// XCD-chunked bijective block swizzle (T1). Requires nwg % 8 == 0.
__device__ __forceinline__ void xcd_swizzle(int& bx, int& by)
{
    const int nx = gridDim.x, nwg = nx * gridDim.y;
    const int lin = blockIdx.y * nx + blockIdx.x;
    const int cpx = nwg >> 3;                    // blocks per XCD chunk
    const int swz = (lin & 7) * cpx + (lin >> 3);
    bx = swz % nx; by = swz / nx;
}

// ---------------------------------------------------------------------------
// fcast: flat fp32 -> f16
// ---------------------------------------------------------------------------
__global__ __launch_bounds__(256)
void fcast_k(const float* __restrict__ in, unsigned short* __restrict__ out, int n4)
{
    int i = blockIdx.x * 256 + threadIdx.x;
    if (i < n4) {
        float4 v = *(const float4*)&in[i * 4];
        ushort4 o = { f2h_u(v.x), f2h_u(v.y), f2h_u(v.z), f2h_u(v.w) };
        *(ushort4*)&out[i * 4] = o;
    }
}

// ---------------------------------------------------------------------------
// wcast: W[K][N] fp32 -> Wt[N][K] f16, 6 weights via blockIdx.z.
// ---------------------------------------------------------------------------
__global__ __launch_bounds__(256)
void wcast_k(const float* __restrict__ W0, const float* __restrict__ W1,
             const float* __restrict__ W2, const float* __restrict__ W3,
             const float* __restrict__ W4, const float* __restrict__ W5,
             unsigned short* __restrict__ T)
{
    const int z = blockIdx.z;
    const float* W = (z==0)?W0:(z==1)?W1:(z==2)?W2:(z==3)?W3:(z==4)?W4:W5;
    unsigned short* out = T + (size_t)z * DH * DH;

    __shared__ float tile[32][33];
    const int t = threadIdx.x;
    const int n0 = blockIdx.x * 32, k0 = blockIdx.y * 32;
    const int r = t >> 3, c4 = (t & 7) * 4;

    float4 v = *(const float4*)&W[(size_t)(k0 + r) * DH + n0 + c4];
    tile[r][c4 + 0] = v.x; tile[r][c4 + 1] = v.y;
    tile[r][c4 + 2] = v.z; tile[r][c4 + 3] = v.w;
    __syncthreads();

    ushort4 o = { f2h_u(tile[c4 + 0][r]), f2h_u(tile[c4 + 1][r]),
                  f2h_u(tile[c4 + 2][r]), f2h_u(tile[c4 + 3][r]) };
    *(ushort4*)&out[(size_t)(n0 + r) * DH + k0 + c4] = o;
}

// ---------------------------------------------------------------------------
// f16 MFMA GEMM (R9-verified structure): C = A @ Wt^T + bias. BK=64,
// 128x64 tile, global_load_lds staging with XOR-swizzled layout
// (linear dest + inverse-swz source + swz read). + XCD block swizzle.
// ---------------------------------------------------------------------------
#define BM 128
#define BN 64
#define BK 64

template<bool GELU, bool WF32, bool WF16>
__global__ __launch_bounds__(256)
void gemm_f16_k(const unsigned short* __restrict__ Ab,
                const unsigned short* __restrict__ Bt0,
                const unsigned short* __restrict__ Bt1,
                const unsigned short* __restrict__ Bt2,
                const float* __restrict__ bi0, const float* __restrict__ bi1,
                const float* __restrict__ bi2,
                float* __restrict__ Cf0, float* __restrict__ Cf1, float* __restrict__ Cf2,
                unsigned short* __restrict__ Ch0, unsigned short* __restrict__ Ch1,
                unsigned short* __restrict__ Ch2)
{
    const int z = blockIdx.z;
    const unsigned short* Bt = (z==0)?Bt0:(z==1)?Bt1:Bt2;
    const float* bi = (z==0)?bi0:(z==1)?bi1:bi2;
    float* Cf = (z==0)?Cf0:(z==1)?Cf1:Cf2;
    unsigned short* Ch = (z==0)?Ch0:(z==1)?Ch1:Ch2;

    __shared__ __align__(16) unsigned short As[BM * BK];  // 16384 B, linear
    __shared__ __align__(16) unsigned short Bs[BN * BK];  //  8192 B, linear

    const int tid = threadIdx.x;
    const int lane = tid & 63, w = tid >> 6;
    int bx, by; xcd_swizzle(bx, by);
    const int bm = by * BM, bn = bx * BN;
    const int wm = (w >> 1) * 64, wn = (w & 1) * 32;

    const int lr8 = lane >> 3;                 // row&7 within chunk
    const int sgrp = ((lane & 7) ^ lr8) * 8;   // inverse-swizzled source group

    const int fl_m = lane & 15, quad = lane >> 4;
    const int rs = fl_m & 7;
    const int g0 = (quad ^ rs) * 8;

    floatx4 acc[4][2] = {};

    for (int k0 = 0; k0 < DH; k0 += BK) {
        __syncthreads();
        #pragma unroll
        for (int c = 0; c < 4; c++) {          // A: 4 chunks/wave
            int rowb = (c * 4 + w) * 8;
            gl_lds16(&Ab[(size_t)(bm + rowb + lr8) * DH + k0 + sgrp],
                     &As[(c * 4 + w) * 512]);
        }
        #pragma unroll
        for (int c = 0; c < 2; c++) {          // B: 2 chunks/wave
            int rowb = (c * 4 + w) * 8;
            gl_lds16(&Bt[(size_t)(bn + rowb + lr8) * DH + k0 + sgrp],
                     &Bs[(c * 4 + w) * 512]);
        }
        __syncthreads();

        f16x8 af[2][4], bf[2][2];
        #pragma unroll
        for (int kk = 0; kk < 2; kk++) {
            const int gg = g0 ^ (kk * 32);
            #pragma unroll
            for (int mt = 0; mt < 4; mt++)
                af[kk][mt] = *(const f16x8*)&As[(wm + mt * 16 + fl_m) * 64 + gg];
            #pragma unroll
            for (int nt = 0; nt < 2; nt++)
                bf[kk][nt] = *(const f16x8*)&Bs[(wn + nt * 16 + fl_m) * 64 + gg];
        }

        #pragma unroll
        for (int kk = 0; kk < 2; kk++)
            #pragma unroll
            for (int mt = 0; mt < 4; mt++)
                #pragma unroll
                for (int nt = 0; nt < 2; nt++)
                    acc[mt][nt] = __builtin_amdgcn_mfma_f32_16x16x32_f16(
                        af[kk][mt], bf[kk][nt], acc[mt][nt], 0, 0, 0);
    }

    const int row_q = (lane >> 4) * 4;
    #pragma unroll
    for (int mt = 0; mt < 4; mt++) {
        #pragma unroll
        for (int nt = 0; nt < 2; nt++) {
            const int col = bn + wn + nt * 16 + fl_m;
            const float bias = bi[col];
            #pragma unroll
            for (int r = 0; r < 4; r++) {
                const int row = bm + wm + mt * 16 + row_q + r;
                float v = acc[mt][nt][r] + bias;
                if (GELU) v = gelu_f(v);
                if (WF32) Cf[(size_t)row * DH + col] = v;
                if (WF16) Ch[(size_t)row * DH + col] = f2h_u(v);
            }
        }
    }
}

// ---------------------------------------------------------------------------
// gemm_qkv3: fused Q/K/V projection. Same verified per-K-step structure as
// gemm_f16_k, but the A tile is staged ONCE and multiplied against the three
// staged weight panels (A HBM traffic for QKV: 490 -> 164 MB). Per-element
// MFMA accumulation order identical to three separate launches.
// ---------------------------------------------------------------------------
__global__ __launch_bounds__(256)
void gemm_qkv3_k(const unsigned short* __restrict__ Ab,
                 const unsigned short* __restrict__ Bq,
                 const unsigned short* __restrict__ Bk,
                 const unsigned short* __restrict__ Bv,
                 const float* __restrict__ bq, const float* __restrict__ bk,
                 const float* __restrict__ bv,
                 unsigned short* __restrict__ Cq, unsigned short* __restrict__ Ck,
                 unsigned short* __restrict__ Cv)
{
    __shared__ __align__(16) unsigned short As[BM * BK];     // 16384 B
    __shared__ __align__(16) unsigned short Bs[3][BN * BK];  // 24576 B

    const int tid = threadIdx.x;
    const int lane = tid & 63, w = tid >> 6;
    int bx, by; xcd_swizzle(bx, by);
    const int bm = by * BM, bn = bx * BN;
    const int wm = (w >> 1) * 64, wn = (w & 1) * 32;

    const int lr8 = lane >> 3;
    const int sgrp = ((lane & 7) ^ lr8) * 8;

    const int fl_m = lane & 15, quad = lane >> 4;
    const int rs = fl_m & 7;
    const int g0 = (quad ^ rs) * 8;

    floatx4 acc[3][4][2] = {};

    for (int k0 = 0; k0 < DH; k0 += BK) {
        __syncthreads();
        #pragma unroll
        for (int c = 0; c < 4; c++) {          // A: 4 chunks/wave (staged once)
            int rowb = (c * 4 + w) * 8;
            gl_lds16(&Ab[(size_t)(bm + rowb + lr8) * DH + k0 + sgrp],
                     &As[(c * 4 + w) * 512]);
        }
        #pragma unroll
        for (int c = 0; c < 2; c++) {          // B: 2 chunks/wave per weight
            int rowb = (c * 4 + w) * 8;
            const size_t src = (size_t)(bn + rowb + lr8) * DH + k0 + sgrp;
            gl_lds16(&Bq[src], &Bs[0][(c * 4 + w) * 512]);
            gl_lds16(&Bk[src], &Bs[1][(c * 4 + w) * 512]);
            gl_lds16(&Bv[src], &Bs[2][(c * 4 + w) * 512]);
        }
        __syncthreads();

        #pragma unroll
        for (int kk = 0; kk < 2; kk++) {
            const int gg = g0 ^ (kk * 32);
            f16x8 af[4];
            #pragma unroll
            for (int mt = 0; mt < 4; mt++)
                af[mt] = *(const f16x8*)&As[(wm + mt * 16 + fl_m) * 64 + gg];
            #pragma unroll
            for (int z = 0; z < 3; z++) {
                f16x8 bf[2];
                #pragma unroll
                for (int nt = 0; nt < 2; nt++)
                    bf[nt] = *(const f16x8*)&Bs[z][(wn + nt * 16 + fl_m) * 64 + gg];
                #pragma unroll
                for (int mt = 0; mt < 4; mt++)
                    #pragma unroll
                    for (int nt = 0; nt < 2; nt++)
                        acc[z][mt][nt] = __builtin_amdgcn_mfma_f32_16x16x32_f16(
                            af[mt], bf[nt], acc[z][mt][nt], 0, 0, 0);
            }
        }
    }

    const int row_q = (lane >> 4) * 4;
    #pragma unroll
    for (int z = 0; z < 3; z++) {
        const float* bi = (z==0)?bq:(z==1)?bk:bv;
        unsigned short* Ch = (z==0)?Cq:(z==1)?Ck:Cv;
        #pragma unroll
        for (int mt = 0; mt < 4; mt++) {
            #pragma unroll
            for (int nt = 0; nt < 2; nt++) {
                const int col = bn + wn + nt * 16 + fl_m;
                const float bias = bi[col];
                #pragma unroll
                for (int r = 0; r < 4; r++) {
                    const int row = bm + wm + mt * 16 + row_q + r;
                    Ch[(size_t)row * DH + col] = f2h_u(acc[z][mt][nt][r] + bias);
                }
            }
        }
    }
}

// ---------------------------------------------------------------------------
// MFMA relation-aware attention — VERBATIM R0 baseline (passed @467 µs).
// FROZEN: every restructure attempt (R1-R4, R6, R7) died with an
// unwritten-output signature regardless of semantics. Do not modify.
// ---------------------------------------------------------------------------
__global__ __launch_bounds__(256, 1)
void attn_k(const unsigned short* __restrict__ Qg,
            const unsigned short* __restrict__ Kg,
            const unsigned short* __restrict__ Vg,
            const float* __restrict__ relk, const float* __restrict__ relv,
            const int* __restrict__ RM, unsigned short* __restrict__ CTX)
{
    __shared__ union {
        unsigned short Kb[512 * 40];   // 40960 B  (score phase)
        unsigned short VT[32 * 520];   // 33280 B  (PV phase)
        float          qf[64 * 36];    // 36864 B  (qrel phase)
    } big;
    __shared__ unsigned char rmb[64 * 516];    // 33024 B
    __shared__ float qrel[64 * 101];           // 25856 B
    __shared__ float wsum[64 * 101];           // 25856 B
    __shared__ float relb[NREL * 36];          // 14400 B (rel_k then rel_v)
    __shared__ unsigned short Pb[4][2][16 * 40]; // 10240 B

    const int tid = threadIdx.x;
    const int w = tid >> 6, lane = tid & 63;
    const int cl = lane & 15, quad = lane >> 4;
    const int b = blockIdx.z, h = blockIdx.y, q0 = blockIdx.x * 64;
    const float scale = 0.17677669529663689f;   // 1/sqrt(32)

    // ---------------- P0 ----------------
    for (int i = tid; i < 64 * 101; i += 256) wsum[i] = 0.f;
    {   // q tile -> fp32 LDS [64][36]
        int row = tid >> 2, g = tid & 3;
        uint4 qv = *(const uint4*)&Qg[(size_t)(b * S_ + q0 + row) * DH + h * PH + g * 8];
        f16x8 qh = __builtin_bit_cast(f16x8, qv);
        #pragma unroll
        for (int j = 0; j < 8; j++) big.qf[row * 36 + g * 8 + j] = (float)qh[j];
    }
    for (int i = tid; i < NREL * 8; i += 256) {   // rel_k fp32 [100][36]
        int r = i >> 3, dg = i & 7;
        *(float4*)&relb[r * 36 + dg * 4] = *(const float4*)&relk[r * PH + dg * 4];
    }
    #pragma unroll
    for (int it = 0; it < 32; it++) {   // rm -> u8 [64][516]
        int idx = it * 256 + tid;
        int key4 = idx & 127, ql = idx >> 7;
        int4 rv = *(const int4*)&RM[(size_t)(b * S_ + q0 + ql) * S_ + key4 * 4];
        uchar4 o = { (unsigned char)rv.x, (unsigned char)rv.y,
                     (unsigned char)rv.z, (unsigned char)rv.w };
        *(uchar4*)&rmb[ql * 516 + key4 * 4] = o;
    }
    __syncthreads();

    // ---------------- P1: qrel[q][r] ----------------
    {
        const int q = tid >> 2, rsub = tid & 3;
        float qv[PH];
        #pragma unroll
        for (int d = 0; d < PH; d++) qv[d] = big.qf[q * 36 + d];
        for (int i = 0; i < 25; i++) {
            int r = rsub * 25 + i;
            float s = 0.f;
            #pragma unroll
            for (int d = 0; d < PH; d++) s += qv[d] * relb[r * 36 + d];
            qrel[q * 101 + r] = s;
        }
    }
    __syncthreads();

    // ---------------- P2: stage K rows + rel_v ----------------
    #pragma unroll
    for (int it = 0; it < 8; it++) {
        int idx = it * 256 + tid;
        int key = idx >> 2, g = idx & 3;
        uint4 kv = *(const uint4*)&Kg[(size_t)(b * S_ + key) * DH + h * PH + g * 8];
        *(uint4*)&big.Kb[key * 40 + g * 8] = kv;
    }
    for (int i = tid; i < NREL * 8; i += 256) {
        int r = i >> 3, dg = i & 7;
        *(float4*)&relb[r * 36 + dg * 4] = *(const float4*)&relv[r * PH + dg * 4];
    }
    __syncthreads();

    // ---------------- P3: scores + bias + softmax + scatter ----------------
    floatx4 acc[32];
    {
        f16x8 qa = __builtin_bit_cast(f16x8, *(const uint4*)
            &Qg[(size_t)(b * S_ + q0 + w * 16 + cl) * DH + h * PH + quad * 8]);
        #pragma unroll
        for (int t = 0; t < 32; t++) {
            f16x8 kf = *(const f16x8*)&big.Kb[(t * 16 + cl) * 40 + quad * 8];
            acc[t] = __builtin_amdgcn_mfma_f32_16x16x32_f16(qa, kf, (floatx4){}, 0, 0, 0);
        }
        // bias + scale (C layout: col=key=cl+16t, row=q= w*16+quad*4+r)
        #pragma unroll
        for (int t = 0; t < 32; t++) {
            #pragma unroll
            for (int r = 0; r < 4; r++) {
                int ql = w * 16 + quad * 4 + r;
                int rm = rmb[ql * 516 + t * 16 + cl];
                acc[t][r] = (acc[t][r] + qrel[ql * 101 + rm]) * scale;
            }
        }
        // softmax per row (4 rows in parallel, reduce over 32 regs + 16 lanes)
        float mx[4] = {-1e30f, -1e30f, -1e30f, -1e30f};
        #pragma unroll
        for (int t = 0; t < 32; t++)
            #pragma unroll
            for (int r = 0; r < 4; r++) mx[r] = fmaxf(mx[r], acc[t][r]);
        #pragma unroll
        for (int r = 0; r < 4; r++) {
            #pragma unroll
            for (int off = 1; off < 16; off <<= 1)
                mx[r] = fmaxf(mx[r], __shfl_xor(mx[r], off));
        }
        float sm[4] = {};
        #pragma unroll
        for (int t = 0; t < 32; t++)
            #pragma unroll
            for (int r = 0; r < 4; r++) {
                float e = __expf(acc[t][r] - mx[r]);
                acc[t][r] = e; sm[r] += e;
            }
        #pragma unroll
        for (int r = 0; r < 4; r++) {
            #pragma unroll
            for (int off = 1; off < 16; off <<= 1)
                sm[r] += __shfl_xor(sm[r], off);
            sm[r] = 1.0f / sm[r];
        }
        #pragma unroll
        for (int t = 0; t < 32; t++)
            #pragma unroll
            for (int r = 0; r < 4; r++) acc[t][r] *= sm[r];
        // wsum scatter
        #pragma unroll
        for (int t = 0; t < 32; t++) {
            #pragma unroll
            for (int r = 0; r < 4; r++) {
                int ql = w * 16 + quad * 4 + r;
                int rm = rmb[ql * 516 + t * 16 + cl];
                atomicAdd(&wsum[ql * 101 + rm], acc[t][r]);
            }
        }
    }
    __syncthreads();

    // ---------------- P4: stage V^T [32 d][520 keys] ----------------
    #pragma unroll
    for (int it = 0; it < 8; it++) {
        int idx = it * 256 + tid;
        int key = idx >> 2, part = idx & 3;
        uint4 vv = *(const uint4*)&Vg[(size_t)(b * S_ + key) * DH + h * PH + part * 8];
        f16x8 vh = __builtin_bit_cast(f16x8, vv);
        #pragma unroll
        for (int j = 0; j < 8; j++)
            big.VT[(part * 8 + j) * 520 + key] = f2h_u((float)vh[j]) , (void)0;
    }
    __syncthreads();

    // ---------------- P5: PV + ctx_rel + write ----------------
    {
        floatx4 ctx[2] = {};
        #pragma unroll
        for (int c = 0; c < 16; c++) {
            // write P chunk (32 keys) to per-wave buffer, C-layout -> rows
            #pragma unroll
            for (int tt = 0; tt < 2; tt++) {
                #pragma unroll
                for (int r = 0; r < 4; r++)
                    Pb[w][c & 1][(quad * 4 + r) * 40 + tt * 16 + cl] =
                        f2h_u(acc[c * 2 + tt][r]);
            }
            f16x8 pa = *(const f16x8*)&Pb[w][c & 1][cl * 40 + quad * 8];
            #pragma unroll
            for (int nt = 0; nt < 2; nt++) {
                f16x8 vf = *(const f16x8*)&big.VT[(nt * 16 + cl) * 520 + c * 32 + quad * 8];
                ctx[nt] = __builtin_amdgcn_mfma_f32_16x16x32_f16(pa, vf, ctx[nt], 0, 0, 0);
            }
        }
        // ctx_rel = wsum @ rel_v
        for (int r = 0; r < NREL; r++) {
            float rv0 = relb[r * 36 + cl];
            float rv1 = relb[r * 36 + 16 + cl];
            #pragma unroll
            for (int rr = 0; rr < 4; rr++) {
                float ws = wsum[(w * 16 + quad * 4 + rr) * 101 + r];
                ctx[0][rr] += ws * rv0;
                ctx[1][rr] += ws * rv1;
            }
        }
        #pragma unroll
        for (int nt = 0; nt < 2; nt++) {
            #pragma unroll
            for (int rr = 0; rr < 4; rr++) {
                int row = b * S_ + q0 + w * 16 + quad * 4 + rr;
                int col = h * PH + nt * 16 + cl;
                CTX[(size_t)row * DH + col] = f2h_u(ctx[nt][rr]);
            }
        }
    }
}

// ---------------------------------------------------------------------------
extern "C" void kernel_launch(void* const* d_in, const int* in_sizes, int n_in,
                              void* d_out, int out_size, void* d_ws, size_t ws_size,
                              hipStream_t stream)
{
    const float* hidden = (const float*)d_in[0];
    const float* Wq = (const float*)d_in[1];  const float* bq = (const float*)d_in[2];
    const float* Wk = (const float*)d_in[3];  const float* bk = (const float*)d_in[4];
    const float* Wv = (const float*)d_in[5];  const float* bv = (const float*)d_in[6];
    const float* Wo = (const float*)d_in[7];  const float* bo = (const float*)d_in[8];
    const float* relk = (const float*)d_in[9];
    const float* relv = (const float*)d_in[10];
    const float* W1 = (const float*)d_in[11]; const float* b1 = (const float*)d_in[12];
    const float* W2 = (const float*)d_in[13]; const float* b2 = (const float*)d_in[14];
    const int*   RM = (const int*)d_in[15];
    float* out = (float*)d_out;

    const size_t SZ = (size_t)MROWS * DH;          // 3,276,800 elems
    const size_t SZB = SZ * 2;                     // f16 bytes

    char* ws = (char*)d_ws;
    unsigned short* hb   = (unsigned short*)(ws);              // hidden f16
    unsigned short* qf   = (unsigned short*)(ws + SZB);        // q f16
    unsigned short* kf   = (unsigned short*)(ws + 2*SZB);      // k f16
    unsigned short* vf   = (unsigned short*)(ws + 3*SZB);      // v f16
    unsigned short* ctxf = (unsigned short*)(ws + 4*SZB);      // ctx f16
    unsigned short* aof  = (unsigned short*)(ws + 5*SZB);      // attn_out f16
    unsigned short* hff  = (unsigned short*)(ws + 6*SZB);      // ffn hidden f16
    unsigned short* Wt   = (unsigned short*)(ws + 7*SZB);      // 6 x [N][K] f16
    const size_t WSZ = (size_t)DH * DH;
    unsigned short *Wtq = Wt,         *Wtk = Wt + WSZ,   *Wtv = Wt + 2*WSZ,
                   *Wto = Wt + 3*WSZ, *Wt1 = Wt + 4*WSZ, *Wt2 = Wt + 5*WSZ;

    fcast_k<<<dim3((SZ/4 + 255)/256), 256, 0, stream>>>(hidden, hb, (int)(SZ/4));
    wcast_k<<<dim3(DH/32, DH/32, 6), 256, 0, stream>>>(Wq, Wk, Wv, Wo, W1, W2, Wt);

    // QKV fused (A staged once per tile) — grid 25x16 = 400 blocks
    gemm_qkv3_k<<<dim3(DH/BN, MROWS/BM), 256, 0, stream>>>(
        hb, Wtq, Wtk, Wtv, bq, bk, bv, qf, kf, vf);

    attn_k<<<dim3(S_/64, NH, B_), 256, 0, stream>>>(qf, kf, vf, relk, relv, RM, ctxf);

    // attn_out = ctx @ Wo + bo
    gemm_f16_k<false, false, true><<<dim3(DH/BN, MROWS/BM, 1), 256, 0, stream>>>(
        ctxf, Wto, Wto, Wto, bo, bo, bo,
        nullptr, nullptr, nullptr, aof, aof, aof);

    // h = gelu(attn_out @ W1 + b1)
    gemm_f16_k<true, false, true><<<dim3(DH/BN, MROWS/BM, 1), 256, 0, stream>>>(
        aof, Wt1, Wt1, Wt1, b1, b1, b1,
        nullptr, nullptr, nullptr, hff, hff, hff);

    // out = h @ W2 + b2  (fp32 out)
    gemm_f16_k<false, true, false><<<dim3(DH/BN, MROWS/BM, 1), 256, 0, stream>>>(
        hff, Wt2, Wt2, Wt2, b2, b2, b2,
        out, out, out, nullptr, nullptr, nullptr);
}

// Round 11
// 712.132 us; speedup vs baseline: 1.0409x; 1.0068x over previous
//
#include <hip/hip_runtime.h>
#include <math.h>

#define B_   4
#define S_   512
#define DH   1600
#define NH   50
#define PH   32
#define NREL 100
#define MROWS (B_ * S_)          // 2048

typedef _Float16 f16x8 __attribute__((ext_vector_type(8)));
typedef float  floatx4 __attribute__((ext_vector_type(4)));

__device__ __forceinline__ float gelu_f(float x) {
    return 0.5f * x * (1.0f + erff(x * 0.70710678118654752f));
}

__device__ __forceinline__ unsigned short f2h_u(float f) {
    _Float16 h = (_Float16)f;
    return __builtin_bit_cast(unsigned short, h);
}

// global -> LDS direct copy, 16 B per lane (gfx950 global_load_lds_dwordx4).
typedef const __attribute__((address_space(1))) unsigned int guint;
typedef __attribute__((address_space(3))) unsigned int luint;
__device__ __forceinline__ void gl_lds16(const unsigned short* g, unsigned short* l)
{
    __builtin_amdgcn_global_load_lds((guint*)g, (luint*)l, 16, 0, 0);
}

// XCD-chunked bijective block swizzle (T1). Requires nwg % 8 == 0.
__device__ __forceinline__ void xcd_swizzle(int& bx, int& by)
{
    const int nx = gridDim.x, nwg = nx * gridDim.y;
    const int lin = blockIdx.y * nx + blockIdx.x;
    const int cpx = nwg >> 3;                    // blocks per XCD chunk
    const int swz = (lin & 7) * cpx + (lin >> 3);
    bx = swz % nx; by = swz / nx;
}

// ---------------------------------------------------------------------------
// fcast: flat fp32 -> f16
// ---------------------------------------------------------------------------
__global__ __launch_bounds__(256)
void fcast_k(const float* __restrict__ in, unsigned short* __restrict__ out, int n4)
{
    int i = blockIdx.x * 256 + threadIdx.x;
    if (i < n4) {
        float4 v = *(const float4*)&in[i * 4];
        ushort4 o = { f2h_u(v.x), f2h_u(v.y), f2h_u(v.z), f2h_u(v.w) };
        *(ushort4*)&out[i * 4] = o;
    }
}

// ---------------------------------------------------------------------------
// wcast: W[K][N] fp32 -> Wt[N][K] f16, 6 weights via blockIdx.z.
// ---------------------------------------------------------------------------
__global__ __launch_bounds__(256)
void wcast_k(const float* __restrict__ W0, const float* __restrict__ W1,
             const float* __restrict__ W2, const float* __restrict__ W3,
             const float* __restrict__ W4, const float* __restrict__ W5,
             unsigned short* __restrict__ T)
{
    const int z = blockIdx.z;
    const float* W = (z==0)?W0:(z==1)?W1:(z==2)?W2:(z==3)?W3:(z==4)?W4:W5;
    unsigned short* out = T + (size_t)z * DH * DH;

    __shared__ float tile[32][33];
    const int t = threadIdx.x;
    const int n0 = blockIdx.x * 32, k0 = blockIdx.y * 32;
    const int r = t >> 3, c4 = (t & 7) * 4;

    float4 v = *(const float4*)&W[(size_t)(k0 + r) * DH + n0 + c4];
    tile[r][c4 + 0] = v.x; tile[r][c4 + 1] = v.y;
    tile[r][c4 + 2] = v.z; tile[r][c4 + 3] = v.w;
    __syncthreads();

    ushort4 o = { f2h_u(tile[c4 + 0][r]), f2h_u(tile[c4 + 1][r]),
                  f2h_u(tile[c4 + 2][r]), f2h_u(tile[c4 + 3][r]) };
    *(ushort4*)&out[(size_t)(n0 + r) * DH + k0 + c4] = o;
}

// ---------------------------------------------------------------------------
// f16 MFMA GEMM: C = A @ Wt^T + bias. BK=64, 128x64 tile, global_load_lds
// staging (XOR-swizzled layout), XCD block swizzle, and DOUBLE-BUFFERED
// staging (minimum-2-phase): the barrier at the top of iter k drains the
// prefetch issued in iter k-1, so loads fly during the entire compute phase
// instead of being serially exposed (GEMMs are latency-bound at ~1.6
// blocks/CU — R10 post-mortem). MFMA accumulation order unchanged.
// ---------------------------------------------------------------------------
#define BM 128
#define BN 64
#define BK 64

template<bool GELU, bool WF32, bool WF16>
__global__ __launch_bounds__(256)
void gemm_f16_k(const unsigned short* __restrict__ Ab,
                const unsigned short* __restrict__ Bt0,
                const unsigned short* __restrict__ Bt1,
                const unsigned short* __restrict__ Bt2,
                const float* __restrict__ bi0, const float* __restrict__ bi1,
                const float* __restrict__ bi2,
                float* __restrict__ Cf0, float* __restrict__ Cf1, float* __restrict__ Cf2,
                unsigned short* __restrict__ Ch0, unsigned short* __restrict__ Ch1,
                unsigned short* __restrict__ Ch2)
{
    const int z = blockIdx.z;
    const unsigned short* Bt = (z==0)?Bt0:(z==1)?Bt1:Bt2;
    const float* bi = (z==0)?bi0:(z==1)?bi1:bi2;
    float* Cf = (z==0)?Cf0:(z==1)?Cf1:Cf2;
    unsigned short* Ch = (z==0)?Ch0:(z==1)?Ch1:Ch2;

    __shared__ __align__(16) unsigned short As[2][BM * BK];  // 32768 B
    __shared__ __align__(16) unsigned short Bs[2][BN * BK];  // 16384 B

    const int tid = threadIdx.x;
    const int lane = tid & 63, w = tid >> 6;
    int bx, by; xcd_swizzle(bx, by);
    const int bm = by * BM, bn = bx * BN;
    const int wm = (w >> 1) * 64, wn = (w & 1) * 32;

    const int lr8 = lane >> 3;                 // row&7 within chunk
    const int sgrp = ((lane & 7) ^ lr8) * 8;   // inverse-swizzled source group

    const int fl_m = lane & 15, quad = lane >> 4;
    const int rs = fl_m & 7;
    const int g0 = (quad ^ rs) * 8;

    floatx4 acc[4][2] = {};

    // stage tile k0 into buffer buf (6 global_load_lds per thread-wave set)
    auto STAGE = [&](int buf, int k0) {
        #pragma unroll
        for (int c = 0; c < 4; c++) {          // A: 4 chunks/wave
            int rowb = (c * 4 + w) * 8;
            gl_lds16(&Ab[(size_t)(bm + rowb + lr8) * DH + k0 + sgrp],
                     &As[buf][(c * 4 + w) * 512]);
        }
        #pragma unroll
        for (int c = 0; c < 2; c++) {          // B: 2 chunks/wave
            int rowb = (c * 4 + w) * 8;
            gl_lds16(&Bt[(size_t)(bn + rowb + lr8) * DH + k0 + sgrp],
                     &Bs[buf][(c * 4 + w) * 512]);
        }
    };

    STAGE(0, 0);
    int cur = 0;
    for (int k0 = 0; k0 < DH; k0 += BK) {
        __syncthreads();   // drains vmcnt -> buf[cur] populated
        if (k0 + BK < DH) STAGE(cur ^ 1, k0 + BK);   // prefetch next tile

        f16x8 af[2][4], bf[2][2];
        #pragma unroll
        for (int kk = 0; kk < 2; kk++) {
            const int gg = g0 ^ (kk * 32);
            #pragma unroll
            for (int mt = 0; mt < 4; mt++)
                af[kk][mt] = *(const f16x8*)&As[cur][(wm + mt * 16 + fl_m) * 64 + gg];
            #pragma unroll
            for (int nt = 0; nt < 2; nt++)
                bf[kk][nt] = *(const f16x8*)&Bs[cur][(wn + nt * 16 + fl_m) * 64 + gg];
        }

        #pragma unroll
        for (int kk = 0; kk < 2; kk++)
            #pragma unroll
            for (int mt = 0; mt < 4; mt++)
                #pragma unroll
                for (int nt = 0; nt < 2; nt++)
                    acc[mt][nt] = __builtin_amdgcn_mfma_f32_16x16x32_f16(
                        af[kk][mt], bf[kk][nt], acc[mt][nt], 0, 0, 0);
        cur ^= 1;
    }

    const int row_q = (lane >> 4) * 4;
    #pragma unroll
    for (int mt = 0; mt < 4; mt++) {
        #pragma unroll
        for (int nt = 0; nt < 2; nt++) {
            const int col = bn + wn + nt * 16 + fl_m;
            const float bias = bi[col];
            #pragma unroll
            for (int r = 0; r < 4; r++) {
                const int row = bm + wm + mt * 16 + row_q + r;
                float v = acc[mt][nt][r] + bias;
                if (GELU) v = gelu_f(v);
                if (WF32) Cf[(size_t)row * DH + col] = v;
                if (WF16) Ch[(size_t)row * DH + col] = f2h_u(v);
            }
        }
    }
}

// ---------------------------------------------------------------------------
// gemm_qkv3: fused Q/K/V projection (A staged once per tile), double-buffered
// like gemm_f16_k. LDS 81920 B -> 2 blocks/CU.
// ---------------------------------------------------------------------------
__global__ __launch_bounds__(256)
void gemm_qkv3_k(const unsigned short* __restrict__ Ab,
                 const unsigned short* __restrict__ Bq,
                 const unsigned short* __restrict__ Bk,
                 const unsigned short* __restrict__ Bv,
                 const float* __restrict__ bq, const float* __restrict__ bk,
                 const float* __restrict__ bv,
                 unsigned short* __restrict__ Cq, unsigned short* __restrict__ Ck,
                 unsigned short* __restrict__ Cv)
{
    __shared__ __align__(16) unsigned short As[2][BM * BK];     // 32768 B
    __shared__ __align__(16) unsigned short Bs[2][3][BN * BK];  // 49152 B

    const int tid = threadIdx.x;
    const int lane = tid & 63, w = tid >> 6;
    int bx, by; xcd_swizzle(bx, by);
    const int bm = by * BM, bn = bx * BN;
    const int wm = (w >> 1) * 64, wn = (w & 1) * 32;

    const int lr8 = lane >> 3;
    const int sgrp = ((lane & 7) ^ lr8) * 8;

    const int fl_m = lane & 15, quad = lane >> 4;
    const int rs = fl_m & 7;
    const int g0 = (quad ^ rs) * 8;

    floatx4 acc[3][4][2] = {};

    auto STAGE = [&](int buf, int k0) {
        #pragma unroll
        for (int c = 0; c < 4; c++) {          // A: staged once
            int rowb = (c * 4 + w) * 8;
            gl_lds16(&Ab[(size_t)(bm + rowb + lr8) * DH + k0 + sgrp],
                     &As[buf][(c * 4 + w) * 512]);
        }
        #pragma unroll
        for (int c = 0; c < 2; c++) {          // B: 2 chunks/wave per weight
            int rowb = (c * 4 + w) * 8;
            const size_t src = (size_t)(bn + rowb + lr8) * DH + k0 + sgrp;
            gl_lds16(&Bq[src], &Bs[buf][0][(c * 4 + w) * 512]);
            gl_lds16(&Bk[src], &Bs[buf][1][(c * 4 + w) * 512]);
            gl_lds16(&Bv[src], &Bs[buf][2][(c * 4 + w) * 512]);
        }
    };

    STAGE(0, 0);
    int cur = 0;
    for (int k0 = 0; k0 < DH; k0 += BK) {
        __syncthreads();
        if (k0 + BK < DH) STAGE(cur ^ 1, k0 + BK);

        #pragma unroll
        for (int kk = 0; kk < 2; kk++) {
            const int gg = g0 ^ (kk * 32);
            f16x8 af[4];
            #pragma unroll
            for (int mt = 0; mt < 4; mt++)
                af[mt] = *(const f16x8*)&As[cur][(wm + mt * 16 + fl_m) * 64 + gg];
            #pragma unroll
            for (int z = 0; z < 3; z++) {
                f16x8 bf[2];
                #pragma unroll
                for (int nt = 0; nt < 2; nt++)
                    bf[nt] = *(const f16x8*)&Bs[cur][z][(wn + nt * 16 + fl_m) * 64 + gg];
                #pragma unroll
                for (int mt = 0; mt < 4; mt++)
                    #pragma unroll
                    for (int nt = 0; nt < 2; nt++)
                        acc[z][mt][nt] = __builtin_amdgcn_mfma_f32_16x16x32_f16(
                            af[mt], bf[nt], acc[z][mt][nt], 0, 0, 0);
            }
        }
        cur ^= 1;
    }

    const int row_q = (lane >> 4) * 4;
    #pragma unroll
    for (int z = 0; z < 3; z++) {
        const float* bi = (z==0)?bq:(z==1)?bk:bv;
        unsigned short* Ch = (z==0)?Cq:(z==1)?Ck:Cv;
        #pragma unroll
        for (int mt = 0; mt < 4; mt++) {
            #pragma unroll
            for (int nt = 0; nt < 2; nt++) {
                const int col = bn + wn + nt * 16 + fl_m;
                const float bias = bi[col];
                #pragma unroll
                for (int r = 0; r < 4; r++) {
                    const int row = bm + wm + mt * 16 + row_q + r;
                    Ch[(size_t)row * DH + col] = f2h_u(acc[z][mt][nt][r] + bias);
                }
            }
        }
    }
}

// ---------------------------------------------------------------------------
// MFMA relation-aware attention — VERBATIM R0 baseline (passed @467 µs).
// FROZEN: every restructure attempt (R1-R4, R6, R7) died with an
// unwritten-output signature regardless of semantics. Do not modify.
// ---------------------------------------------------------------------------
__global__ __launch_bounds__(256, 1)
void attn_k(const unsigned short* __restrict__ Qg,
            const unsigned short* __restrict__ Kg,
            const unsigned short* __restrict__ Vg,
            const float* __restrict__ relk, const float* __restrict__ relv,
            const int* __restrict__ RM, unsigned short* __restrict__ CTX)
{
    __shared__ union {
        unsigned short Kb[512 * 40];   // 40960 B  (score phase)
        unsigned short VT[32 * 520];   // 33280 B  (PV phase)
        float          qf[64 * 36];    // 36864 B  (qrel phase)
    } big;
    __shared__ unsigned char rmb[64 * 516];    // 33024 B
    __shared__ float qrel[64 * 101];           // 25856 B
    __shared__ float wsum[64 * 101];           // 25856 B
    __shared__ float relb[NREL * 36];          // 14400 B (rel_k then rel_v)
    __shared__ unsigned short Pb[4][2][16 * 40]; // 10240 B

    const int tid = threadIdx.x;
    const int w = tid >> 6, lane = tid & 63;
    const int cl = lane & 15, quad = lane >> 4;
    const int b = blockIdx.z, h = blockIdx.y, q0 = blockIdx.x * 64;
    const float scale = 0.17677669529663689f;   // 1/sqrt(32)

    // ---------------- P0 ----------------
    for (int i = tid; i < 64 * 101; i += 256) wsum[i] = 0.f;
    {   // q tile -> fp32 LDS [64][36]
        int row = tid >> 2, g = tid & 3;
        uint4 qv = *(const uint4*)&Qg[(size_t)(b * S_ + q0 + row) * DH + h * PH + g * 8];
        f16x8 qh = __builtin_bit_cast(f16x8, qv);
        #pragma unroll
        for (int j = 0; j < 8; j++) big.qf[row * 36 + g * 8 + j] = (float)qh[j];
    }
    for (int i = tid; i < NREL * 8; i += 256) {   // rel_k fp32 [100][36]
        int r = i >> 3, dg = i & 7;
        *(float4*)&relb[r * 36 + dg * 4] = *(const float4*)&relk[r * PH + dg * 4];
    }
    #pragma unroll
    for (int it = 0; it < 32; it++) {   // rm -> u8 [64][516]
        int idx = it * 256 + tid;
        int key4 = idx & 127, ql = idx >> 7;
        int4 rv = *(const int4*)&RM[(size_t)(b * S_ + q0 + ql) * S_ + key4 * 4];
        uchar4 o = { (unsigned char)rv.x, (unsigned char)rv.y,
                     (unsigned char)rv.z, (unsigned char)rv.w };
        *(uchar4*)&rmb[ql * 516 + key4 * 4] = o;
    }
    __syncthreads();

    // ---------------- P1: qrel[q][r] ----------------
    {
        const int q = tid >> 2, rsub = tid & 3;
        float qv[PH];
        #pragma unroll
        for (int d = 0; d < PH; d++) qv[d] = big.qf[q * 36 + d];
        for (int i = 0; i < 25; i++) {
            int r = rsub * 25 + i;
            float s = 0.f;
            #pragma unroll
            for (int d = 0; d < PH; d++) s += qv[d] * relb[r * 36 + d];
            qrel[q * 101 + r] = s;
        }
    }
    __syncthreads();

    // ---------------- P2: stage K rows + rel_v ----------------
    #pragma unroll
    for (int it = 0; it < 8; it++) {
        int idx = it * 256 + tid;
        int key = idx >> 2, g = idx & 3;
        uint4 kv = *(const uint4*)&Kg[(size_t)(b * S_ + key) * DH + h * PH + g * 8];
        *(uint4*)&big.Kb[key * 40 + g * 8] = kv;
    }
    for (int i = tid; i < NREL * 8; i += 256) {
        int r = i >> 3, dg = i & 7;
        *(float4*)&relb[r * 36 + dg * 4] = *(const float4*)&relv[r * PH + dg * 4];
    }
    __syncthreads();

    // ---------------- P3: scores + bias + softmax + scatter ----------------
    floatx4 acc[32];
    {
        f16x8 qa = __builtin_bit_cast(f16x8, *(const uint4*)
            &Qg[(size_t)(b * S_ + q0 + w * 16 + cl) * DH + h * PH + quad * 8]);
        #pragma unroll
        for (int t = 0; t < 32; t++) {
            f16x8 kf = *(const f16x8*)&big.Kb[(t * 16 + cl) * 40 + quad * 8];
            acc[t] = __builtin_amdgcn_mfma_f32_16x16x32_f16(qa, kf, (floatx4){}, 0, 0, 0);
        }
        // bias + scale (C layout: col=key=cl+16t, row=q= w*16+quad*4+r)
        #pragma unroll
        for (int t = 0; t < 32; t++) {
            #pragma unroll
            for (int r = 0; r < 4; r++) {
                int ql = w * 16 + quad * 4 + r;
                int rm = rmb[ql * 516 + t * 16 + cl];
                acc[t][r] = (acc[t][r] + qrel[ql * 101 + rm]) * scale;
            }
        }
        // softmax per row (4 rows in parallel, reduce over 32 regs + 16 lanes)
        float mx[4] = {-1e30f, -1e30f, -1e30f, -1e30f};
        #pragma unroll
        for (int t = 0; t < 32; t++)
            #pragma unroll
            for (int r = 0; r < 4; r++) mx[r] = fmaxf(mx[r], acc[t][r]);
        #pragma unroll
        for (int r = 0; r < 4; r++) {
            #pragma unroll
            for (int off = 1; off < 16; off <<= 1)
                mx[r] = fmaxf(mx[r], __shfl_xor(mx[r], off));
        }
        float sm[4] = {};
        #pragma unroll
        for (int t = 0; t < 32; t++)
            #pragma unroll
            for (int r = 0; r < 4; r++) {
                float e = __expf(acc[t][r] - mx[r]);
                acc[t][r] = e; sm[r] += e;
            }
        #pragma unroll
        for (int r = 0; r < 4; r++) {
            #pragma unroll
            for (int off = 1; off < 16; off <<= 1)
                sm[r] += __shfl_xor(sm[r], off);
            sm[r] = 1.0f / sm[r];
        }
        #pragma unroll
        for (int t = 0; t < 32; t++)
            #pragma unroll
            for (int r = 0; r < 4; r++) acc[t][r] *= sm[r];
        // wsum scatter
        #pragma unroll
        for (int t = 0; t < 32; t++) {
            #pragma unroll
            for (int r = 0; r < 4; r++) {
                int ql = w * 16 + quad * 4 + r;
                int rm = rmb[ql * 516 + t * 16 + cl];
                atomicAdd(&wsum[ql * 101 + rm], acc[t][r]);
            }
        }
    }
    __syncthreads();

    // ---------------- P4: stage V^T [32 d][520 keys] ----------------
    #pragma unroll
    for (int it = 0; it < 8; it++) {
        int idx = it * 256 + tid;
        int key = idx >> 2, part = idx & 3;
        uint4 vv = *(const uint4*)&Vg[(size_t)(b * S_ + key) * DH + h * PH + part * 8];
        f16x8 vh = __builtin_bit_cast(f16x8, vv);
        #pragma unroll
        for (int j = 0; j < 8; j++)
            big.VT[(part * 8 + j) * 520 + key] = f2h_u((float)vh[j]) , (void)0;
    }
    __syncthreads();

    // ---------------- P5: PV + ctx_rel + write ----------------
    {
        floatx4 ctx[2] = {};
        #pragma unroll
        for (int c = 0; c < 16; c++) {
            // write P chunk (32 keys) to per-wave buffer, C-layout -> rows
            #pragma unroll
            for (int tt = 0; tt < 2; tt++) {
                #pragma unroll
                for (int r = 0; r < 4; r++)
                    Pb[w][c & 1][(quad * 4 + r) * 40 + tt * 16 + cl] =
                        f2h_u(acc[c * 2 + tt][r]);
            }
            f16x8 pa = *(const f16x8*)&Pb[w][c & 1][cl * 40 + quad * 8];
            #pragma unroll
            for (int nt = 0; nt < 2; nt++) {
                f16x8 vf = *(const f16x8*)&big.VT[(nt * 16 + cl) * 520 + c * 32 + quad * 8];
                ctx[nt] = __builtin_amdgcn_mfma_f32_16x16x32_f16(pa, vf, ctx[nt], 0, 0, 0);
            }
        }
        // ctx_rel = wsum @ rel_v
        for (int r = 0; r < NREL; r++) {
            float rv0 = relb[r * 36 + cl];
            float rv1 = relb[r * 36 + 16 + cl];
            #pragma unroll
            for (int rr = 0; rr < 4; rr++) {
                float ws = wsum[(w * 16 + quad * 4 + rr) * 101 + r];
                ctx[0][rr] += ws * rv0;
                ctx[1][rr] += ws * rv1;
            }
        }
        #pragma unroll
        for (int nt = 0; nt < 2; nt++) {
            #pragma unroll
            for (int rr = 0; rr < 4; rr++) {
                int row = b * S_ + q0 + w * 16 + quad * 4 + rr;
                int col = h * PH + nt * 16 + cl;
                CTX[(size_t)row * DH + col] = f2h_u(ctx[nt][rr]);
            }
        }
    }
}

// ---------------------------------------------------------------------------
extern "C" void kernel_launch(void* const* d_in, const int* in_sizes, int n_in,
                              void* d_out, int out_size, void* d_ws, size_t ws_size,
                              hipStream_t stream)
{
    const float* hidden = (const float*)d_in[0];
    const float* Wq = (const float*)d_in[1];  const float* bq = (const float*)d_in[2];
    const float* Wk = (const float*)d_in[3];  const float* bk = (const float*)d_in[4];
    const float* Wv = (const float*)d_in[5];  const float* bv = (const float*)d_in[6];
    const float* Wo = (const float*)d_in[7];  const float* bo = (const float*)d_in[8];
    const float* relk = (const float*)d_in[9];
    const float* relv = (const float*)d_in[10];
    const float* W1 = (const float*)d_in[11]; const float* b1 = (const float*)d_in[12];
    const float* W2 = (const float*)d_in[13]; const float* b2 = (const float*)d_in[14];
    const int*   RM = (const int*)d_in[15];
    float* out = (float*)d_out;

    const size_t SZ = (size_t)MROWS * DH;          // 3,276,800 elems
    const size_t SZB = SZ * 2;                     // f16 bytes

    char* ws = (char*)d_ws;
    unsigned short* hb   = (unsigned short*)(ws);              // hidden f16
    unsigned short* qf   = (unsigned short*)(ws + SZB);        // q f16
    unsigned short* kf   = (unsigned short*)(ws + 2*SZB);      // k f16
    unsigned short* vf   = (unsigned short*)(ws + 3*SZB);      // v f16
    unsigned short* ctxf = (unsigned short*)(ws + 4*SZB);      // ctx f16
    unsigned short* aof  = (unsigned short*)(ws + 5*SZB);      // attn_out f16
    unsigned short* hff  = (unsigned short*)(ws + 6*SZB);      // ffn hidden f16
    unsigned short* Wt   = (unsigned short*)(ws + 7*SZB);      // 6 x [N][K] f16
    const size_t WSZ = (size_t)DH * DH;
    unsigned short *Wtq = Wt,         *Wtk = Wt + WSZ,   *Wtv = Wt + 2*WSZ,
                   *Wto = Wt + 3*WSZ, *Wt1 = Wt + 4*WSZ, *Wt2 = Wt + 5*WSZ;

    fcast_k<<<dim3((SZ/4 + 255)/256), 256, 0, stream>>>(hidden, hb, (int)(SZ/4));
    wcast_k<<<dim3(DH/32, DH/32, 6), 256, 0, stream>>>(Wq, Wk, Wv, Wo, W1, W2, Wt);

    // QKV fused (A staged once per tile) — grid 25x16 = 400 blocks
    gemm_qkv3_k<<<dim3(DH/BN, MROWS/BM), 256, 0, stream>>>(
        hb, Wtq, Wtk, Wtv, bq, bk, bv, qf, kf, vf);

    attn_k<<<dim3(S_/64, NH, B_), 256, 0, stream>>>(qf, kf, vf, relk, relv, RM, ctxf);

    // attn_out = ctx @ Wo + bo
    gemm_f16_k<false, false, true><<<dim3(DH/BN, MROWS/BM, 1), 256, 0, stream>>>(
        ctxf, Wto, Wto, Wto, bo, bo, bo,
        nullptr, nullptr, nullptr, aof, aof, aof);

    // h = gelu(attn_out @ W1 + b1)
    gemm_f16_k<true, false, true><<<dim3(DH/BN, MROWS/BM, 1), 256, 0, stream>>>(
        aof, Wt1, Wt1, Wt1, b1, b1, b1,
        nullptr, nullptr, nullptr, hff, hff, hff);

    // out = h @ W2 + b2  (fp32 out)
    gemm_f16_k<false, true, false><<<dim3(DH/BN, MROWS/BM, 1), 256, 0, stream>>>(
        hff, Wt2, Wt2, Wt2, b2, b2, b2,
        out, out, out, nullptr, nullptr, nullptr);
}

// Round 12
// 702.804 us; speedup vs baseline: 1.0547x; 1.0133x over previous
//
#include <hip/hip_runtime.h>
#include <math.h>

#define B_   4
#define S_   512
#define DH   1600
#define NH   50
#define PH   32
#define NREL 100
#define MROWS (B_ * S_)          // 2048

typedef _Float16 f16x8 __attribute__((ext_vector_type(8)));
typedef float  floatx4 __attribute__((ext_vector_type(4)));

__device__ __forceinline__ float gelu_f(float x) {
    return 0.5f * x * (1.0f + erff(x * 0.70710678118654752f));
}

__device__ __forceinline__ unsigned short f2h_u(float f) {
    _Float16 h = (_Float16)f;
    return __builtin_bit_cast(unsigned short, h);
}

// global -> LDS direct copy, 16 B per lane (gfx950 global_load_lds_dwordx4).
typedef const __attribute__((address_space(1))) unsigned int guint;
typedef __attribute__((address_space(3))) unsigned int luint;
__device__ __forceinline__ void gl_lds16(const unsigned short* g, unsigned short* l)
{
    __builtin_amdgcn_global_load_lds((guint*)g, (luint*)l, 16, 0, 0);
}

// XCD-chunked bijective block swizzle (T1). Requires nwg % 8 == 0.
__device__ __forceinline__ void xcd_swizzle(int& bx, int& by)
{
    const int nx = gridDim.x, nwg = nx * gridDim.y;
    const int lin = blockIdx.y * nx + blockIdx.x;
    const int cpx = nwg >> 3;                    // blocks per XCD chunk
    const int swz = (lin & 7) * cpx + (lin >> 3);
    bx = swz % nx; by = swz / nx;
}

// ---------------------------------------------------------------------------
// fcast: flat fp32 -> f16
// ---------------------------------------------------------------------------
__global__ __launch_bounds__(256)
void fcast_k(const float* __restrict__ in, unsigned short* __restrict__ out, int n4)
{
    int i = blockIdx.x * 256 + threadIdx.x;
    if (i < n4) {
        float4 v = *(const float4*)&in[i * 4];
        ushort4 o = { f2h_u(v.x), f2h_u(v.y), f2h_u(v.z), f2h_u(v.w) };
        *(ushort4*)&out[i * 4] = o;
    }
}

// ---------------------------------------------------------------------------
// wcast: W[K][N] fp32 -> Wt[N][K] f16, 6 weights via blockIdx.z.
// ---------------------------------------------------------------------------
__global__ __launch_bounds__(256)
void wcast_k(const float* __restrict__ W0, const float* __restrict__ W1,
             const float* __restrict__ W2, const float* __restrict__ W3,
             const float* __restrict__ W4, const float* __restrict__ W5,
             unsigned short* __restrict__ T)
{
    const int z = blockIdx.z;
    const float* W = (z==0)?W0:(z==1)?W1:(z==2)?W2:(z==3)?W3:(z==4)?W4:W5;
    unsigned short* out = T + (size_t)z * DH * DH;

    __shared__ float tile[32][33];
    const int t = threadIdx.x;
    const int n0 = blockIdx.x * 32, k0 = blockIdx.y * 32;
    const int r = t >> 3, c4 = (t & 7) * 4;

    float4 v = *(const float4*)&W[(size_t)(k0 + r) * DH + n0 + c4];
    tile[r][c4 + 0] = v.x; tile[r][c4 + 1] = v.y;
    tile[r][c4 + 2] = v.z; tile[r][c4 + 3] = v.w;
    __syncthreads();

    ushort4 o = { f2h_u(tile[c4 + 0][r]), f2h_u(tile[c4 + 1][r]),
                  f2h_u(tile[c4 + 2][r]), f2h_u(tile[c4 + 3][r]) };
    *(ushort4*)&out[(size_t)(n0 + r) * DH + k0 + c4] = o;
}

// ---------------------------------------------------------------------------
// f16 MFMA GEMM: C = A @ Wt^T + bias. BK=64, 128x64 tile, global_load_lds
// staging (XOR-swizzled layout), XCD block swizzle, and 3-BUFFER DEPTH-2
// pipeline with counted vmcnt (T3/T4 recipe): s_waitcnt vmcnt(6) retires
// only the current buffer's 6 loads (in-order retirement), keeping the next
// tile's 6 in flight across the barrier — loads get ~2 compute phases to
// cover HBM latency instead of 1. Raw s_barrier (no full drain).
// WAR: buffer staged at iter i was computed at iter i-1; all waves' ds_reads
// for it completed (lgkmcnt before their MFMAs) before crossing barrier i.
// MFMA accumulation order unchanged -> bit-identical results.
// ---------------------------------------------------------------------------
#define BM 128
#define BN 64
#define BK 64

template<bool GELU, bool WF32, bool WF16>
__global__ __launch_bounds__(256)
void gemm_f16_k(const unsigned short* __restrict__ Ab,
                const unsigned short* __restrict__ Bt0,
                const unsigned short* __restrict__ Bt1,
                const unsigned short* __restrict__ Bt2,
                const float* __restrict__ bi0, const float* __restrict__ bi1,
                const float* __restrict__ bi2,
                float* __restrict__ Cf0, float* __restrict__ Cf1, float* __restrict__ Cf2,
                unsigned short* __restrict__ Ch0, unsigned short* __restrict__ Ch1,
                unsigned short* __restrict__ Ch2)
{
    const int z = blockIdx.z;
    const unsigned short* Bt = (z==0)?Bt0:(z==1)?Bt1:Bt2;
    const float* bi = (z==0)?bi0:(z==1)?bi1:bi2;
    float* Cf = (z==0)?Cf0:(z==1)?Cf1:Cf2;
    unsigned short* Ch = (z==0)?Ch0:(z==1)?Ch1:Ch2;

    __shared__ __align__(16) unsigned short As[3][BM * BK];  // 49152 B
    __shared__ __align__(16) unsigned short Bs[3][BN * BK];  // 24576 B

    const int tid = threadIdx.x;
    const int lane = tid & 63, w = tid >> 6;
    int bx, by; xcd_swizzle(bx, by);
    const int bm = by * BM, bn = bx * BN;
    const int wm = (w >> 1) * 64, wn = (w & 1) * 32;

    const int lr8 = lane >> 3;                 // row&7 within chunk
    const int sgrp = ((lane & 7) ^ lr8) * 8;   // inverse-swizzled source group

    const int fl_m = lane & 15, quad = lane >> 4;
    const int rs = fl_m & 7;
    const int g0 = (quad ^ rs) * 8;

    floatx4 acc[4][2] = {};

    // stage tile k0 into buffer buf (6 global_load_lds per thread)
    auto STAGE = [&](int buf, int k0) {
        #pragma unroll
        for (int c = 0; c < 4; c++) {          // A: 4 chunks/wave
            int rowb = (c * 4 + w) * 8;
            gl_lds16(&Ab[(size_t)(bm + rowb + lr8) * DH + k0 + sgrp],
                     &As[buf][(c * 4 + w) * 512]);
        }
        #pragma unroll
        for (int c = 0; c < 2; c++) {          // B: 2 chunks/wave
            int rowb = (c * 4 + w) * 8;
            gl_lds16(&Bt[(size_t)(bn + rowb + lr8) * DH + k0 + sgrp],
                     &Bs[buf][(c * 4 + w) * 512]);
        }
    };

    STAGE(0, 0);
    STAGE(1, BK);
    int cur = 0;
    for (int k0 = 0; k0 < DH; k0 += BK) {
        // retire only the oldest 6 (current buffer); keep next tile in flight
        if (k0 + BK < DH) asm volatile("s_waitcnt vmcnt(6)" ::: "memory");
        else              asm volatile("s_waitcnt vmcnt(0)" ::: "memory");
        __builtin_amdgcn_s_barrier();
        if (k0 + 2 * BK < DH) {
            int nb = cur + 2; if (nb >= 3) nb -= 3;
            STAGE(nb, k0 + 2 * BK);
        }

        f16x8 af[2][4], bf[2][2];
        #pragma unroll
        for (int kk = 0; kk < 2; kk++) {
            const int gg = g0 ^ (kk * 32);
            #pragma unroll
            for (int mt = 0; mt < 4; mt++)
                af[kk][mt] = *(const f16x8*)&As[cur][(wm + mt * 16 + fl_m) * 64 + gg];
            #pragma unroll
            for (int nt = 0; nt < 2; nt++)
                bf[kk][nt] = *(const f16x8*)&Bs[cur][(wn + nt * 16 + fl_m) * 64 + gg];
        }

        #pragma unroll
        for (int kk = 0; kk < 2; kk++)
            #pragma unroll
            for (int mt = 0; mt < 4; mt++)
                #pragma unroll
                for (int nt = 0; nt < 2; nt++)
                    acc[mt][nt] = __builtin_amdgcn_mfma_f32_16x16x32_f16(
                        af[kk][mt], bf[kk][nt], acc[mt][nt], 0, 0, 0);
        cur += 1; if (cur >= 3) cur = 0;
    }

    const int row_q = (lane >> 4) * 4;
    #pragma unroll
    for (int mt = 0; mt < 4; mt++) {
        #pragma unroll
        for (int nt = 0; nt < 2; nt++) {
            const int col = bn + wn + nt * 16 + fl_m;
            const float bias = bi[col];
            #pragma unroll
            for (int r = 0; r < 4; r++) {
                const int row = bm + wm + mt * 16 + row_q + r;
                float v = acc[mt][nt][r] + bias;
                if (GELU) v = gelu_f(v);
                if (WF32) Cf[(size_t)row * DH + col] = v;
                if (WF16) Ch[(size_t)row * DH + col] = f2h_u(v);
            }
        }
    }
}

// ---------------------------------------------------------------------------
// gemm_qkv3: fused Q/K/V projection (A staged once per tile), double-buffered
// depth-1 (3 buffers would be 120 KB -> 1 block/CU, a regression).
// ---------------------------------------------------------------------------
__global__ __launch_bounds__(256)
void gemm_qkv3_k(const unsigned short* __restrict__ Ab,
                 const unsigned short* __restrict__ Bq,
                 const unsigned short* __restrict__ Bk,
                 const unsigned short* __restrict__ Bv,
                 const float* __restrict__ bq, const float* __restrict__ bk,
                 const float* __restrict__ bv,
                 unsigned short* __restrict__ Cq, unsigned short* __restrict__ Ck,
                 unsigned short* __restrict__ Cv)
{
    __shared__ __align__(16) unsigned short As[2][BM * BK];     // 32768 B
    __shared__ __align__(16) unsigned short Bs[2][3][BN * BK];  // 49152 B

    const int tid = threadIdx.x;
    const int lane = tid & 63, w = tid >> 6;
    int bx, by; xcd_swizzle(bx, by);
    const int bm = by * BM, bn = bx * BN;
    const int wm = (w >> 1) * 64, wn = (w & 1) * 32;

    const int lr8 = lane >> 3;
    const int sgrp = ((lane & 7) ^ lr8) * 8;

    const int fl_m = lane & 15, quad = lane >> 4;
    const int rs = fl_m & 7;
    const int g0 = (quad ^ rs) * 8;

    floatx4 acc[3][4][2] = {};

    auto STAGE = [&](int buf, int k0) {
        #pragma unroll
        for (int c = 0; c < 4; c++) {          // A: staged once
            int rowb = (c * 4 + w) * 8;
            gl_lds16(&Ab[(size_t)(bm + rowb + lr8) * DH + k0 + sgrp],
                     &As[buf][(c * 4 + w) * 512]);
        }
        #pragma unroll
        for (int c = 0; c < 2; c++) {          // B: 2 chunks/wave per weight
            int rowb = (c * 4 + w) * 8;
            const size_t src = (size_t)(bn + rowb + lr8) * DH + k0 + sgrp;
            gl_lds16(&Bq[src], &Bs[buf][0][(c * 4 + w) * 512]);
            gl_lds16(&Bk[src], &Bs[buf][1][(c * 4 + w) * 512]);
            gl_lds16(&Bv[src], &Bs[buf][2][(c * 4 + w) * 512]);
        }
    };

    STAGE(0, 0);
    int cur = 0;
    for (int k0 = 0; k0 < DH; k0 += BK) {
        __syncthreads();
        if (k0 + BK < DH) STAGE(cur ^ 1, k0 + BK);

        #pragma unroll
        for (int kk = 0; kk < 2; kk++) {
            const int gg = g0 ^ (kk * 32);
            f16x8 af[4];
            #pragma unroll
            for (int mt = 0; mt < 4; mt++)
                af[mt] = *(const f16x8*)&As[cur][(wm + mt * 16 + fl_m) * 64 + gg];
            #pragma unroll
            for (int z = 0; z < 3; z++) {
                f16x8 bf[2];
                #pragma unroll
                for (int nt = 0; nt < 2; nt++)
                    bf[nt] = *(const f16x8*)&Bs[cur][z][(wn + nt * 16 + fl_m) * 64 + gg];
                #pragma unroll
                for (int mt = 0; mt < 4; mt++)
                    #pragma unroll
                    for (int nt = 0; nt < 2; nt++)
                        acc[z][mt][nt] = __builtin_amdgcn_mfma_f32_16x16x32_f16(
                            af[mt], bf[nt], acc[z][mt][nt], 0, 0, 0);
            }
        }
        cur ^= 1;
    }

    const int row_q = (lane >> 4) * 4;
    #pragma unroll
    for (int z = 0; z < 3; z++) {
        const float* bi = (z==0)?bq:(z==1)?bk:bv;
        unsigned short* Ch = (z==0)?Cq:(z==1)?Ck:Cv;
        #pragma unroll
        for (int mt = 0; mt < 4; mt++) {
            #pragma unroll
            for (int nt = 0; nt < 2; nt++) {
                const int col = bn + wn + nt * 16 + fl_m;
                const float bias = bi[col];
                #pragma unroll
                for (int r = 0; r < 4; r++) {
                    const int row = bm + wm + mt * 16 + row_q + r;
                    Ch[(size_t)row * DH + col] = f2h_u(acc[z][mt][nt][r] + bias);
                }
            }
        }
    }
}

// ---------------------------------------------------------------------------
// MFMA relation-aware attention — VERBATIM R0 baseline (passed @467 µs).
// FROZEN: every restructure attempt (R1-R4, R6, R7) died with an
// unwritten-output signature regardless of semantics. Do not modify.
// ---------------------------------------------------------------------------
__global__ __launch_bounds__(256, 1)
void attn_k(const unsigned short* __restrict__ Qg,
            const unsigned short* __restrict__ Kg,
            const unsigned short* __restrict__ Vg,
            const float* __restrict__ relk, const float* __restrict__ relv,
            const int* __restrict__ RM, unsigned short* __restrict__ CTX)
{
    __shared__ union {
        unsigned short Kb[512 * 40];   // 40960 B  (score phase)
        unsigned short VT[32 * 520];   // 33280 B  (PV phase)
        float          qf[64 * 36];    // 36864 B  (qrel phase)
    } big;
    __shared__ unsigned char rmb[64 * 516];    // 33024 B
    __shared__ float qrel[64 * 101];           // 25856 B
    __shared__ float wsum[64 * 101];           // 25856 B
    __shared__ float relb[NREL * 36];          // 14400 B (rel_k then rel_v)
    __shared__ unsigned short Pb[4][2][16 * 40]; // 10240 B

    const int tid = threadIdx.x;
    const int w = tid >> 6, lane = tid & 63;
    const int cl = lane & 15, quad = lane >> 4;
    const int b = blockIdx.z, h = blockIdx.y, q0 = blockIdx.x * 64;
    const float scale = 0.17677669529663689f;   // 1/sqrt(32)

    // ---------------- P0 ----------------
    for (int i = tid; i < 64 * 101; i += 256) wsum[i] = 0.f;
    {   // q tile -> fp32 LDS [64][36]
        int row = tid >> 2, g = tid & 3;
        uint4 qv = *(const uint4*)&Qg[(size_t)(b * S_ + q0 + row) * DH + h * PH + g * 8];
        f16x8 qh = __builtin_bit_cast(f16x8, qv);
        #pragma unroll
        for (int j = 0; j < 8; j++) big.qf[row * 36 + g * 8 + j] = (float)qh[j];
    }
    for (int i = tid; i < NREL * 8; i += 256) {   // rel_k fp32 [100][36]
        int r = i >> 3, dg = i & 7;
        *(float4*)&relb[r * 36 + dg * 4] = *(const float4*)&relk[r * PH + dg * 4];
    }
    #pragma unroll
    for (int it = 0; it < 32; it++) {   // rm -> u8 [64][516]
        int idx = it * 256 + tid;
        int key4 = idx & 127, ql = idx >> 7;
        int4 rv = *(const int4*)&RM[(size_t)(b * S_ + q0 + ql) * S_ + key4 * 4];
        uchar4 o = { (unsigned char)rv.x, (unsigned char)rv.y,
                     (unsigned char)rv.z, (unsigned char)rv.w };
        *(uchar4*)&rmb[ql * 516 + key4 * 4] = o;
    }
    __syncthreads();

    // ---------------- P1: qrel[q][r] ----------------
    {
        const int q = tid >> 2, rsub = tid & 3;
        float qv[PH];
        #pragma unroll
        for (int d = 0; d < PH; d++) qv[d] = big.qf[q * 36 + d];
        for (int i = 0; i < 25; i++) {
            int r = rsub * 25 + i;
            float s = 0.f;
            #pragma unroll
            for (int d = 0; d < PH; d++) s += qv[d] * relb[r * 36 + d];
            qrel[q * 101 + r] = s;
        }
    }
    __syncthreads();

    // ---------------- P2: stage K rows + rel_v ----------------
    #pragma unroll
    for (int it = 0; it < 8; it++) {
        int idx = it * 256 + tid;
        int key = idx >> 2, g = idx & 3;
        uint4 kv = *(const uint4*)&Kg[(size_t)(b * S_ + key) * DH + h * PH + g * 8];
        *(uint4*)&big.Kb[key * 40 + g * 8] = kv;
    }
    for (int i = tid; i < NREL * 8; i += 256) {
        int r = i >> 3, dg = i & 7;
        *(float4*)&relb[r * 36 + dg * 4] = *(const float4*)&relv[r * PH + dg * 4];
    }
    __syncthreads();

    // ---------------- P3: scores + bias + softmax + scatter ----------------
    floatx4 acc[32];
    {
        f16x8 qa = __builtin_bit_cast(f16x8, *(const uint4*)
            &Qg[(size_t)(b * S_ + q0 + w * 16 + cl) * DH + h * PH + quad * 8]);
        #pragma unroll
        for (int t = 0; t < 32; t++) {
            f16x8 kf = *(const f16x8*)&big.Kb[(t * 16 + cl) * 40 + quad * 8];
            acc[t] = __builtin_amdgcn_mfma_f32_16x16x32_f16(qa, kf, (floatx4){}, 0, 0, 0);
        }
        // bias + scale (C layout: col=key=cl+16t, row=q= w*16+quad*4+r)
        #pragma unroll
        for (int t = 0; t < 32; t++) {
            #pragma unroll
            for (int r = 0; r < 4; r++) {
                int ql = w * 16 + quad * 4 + r;
                int rm = rmb[ql * 516 + t * 16 + cl];
                acc[t][r] = (acc[t][r] + qrel[ql * 101 + rm]) * scale;
            }
        }
        // softmax per row (4 rows in parallel, reduce over 32 regs + 16 lanes)
        float mx[4] = {-1e30f, -1e30f, -1e30f, -1e30f};
        #pragma unroll
        for (int t = 0; t < 32; t++)
            #pragma unroll
            for (int r = 0; r < 4; r++) mx[r] = fmaxf(mx[r], acc[t][r]);
        #pragma unroll
        for (int r = 0; r < 4; r++) {
            #pragma unroll
            for (int off = 1; off < 16; off <<= 1)
                mx[r] = fmaxf(mx[r], __shfl_xor(mx[r], off));
        }
        float sm[4] = {};
        #pragma unroll
        for (int t = 0; t < 32; t++)
            #pragma unroll
            for (int r = 0; r < 4; r++) {
                float e = __expf(acc[t][r] - mx[r]);
                acc[t][r] = e; sm[r] += e;
            }
        #pragma unroll
        for (int r = 0; r < 4; r++) {
            #pragma unroll
            for (int off = 1; off < 16; off <<= 1)
                sm[r] += __shfl_xor(sm[r], off);
            sm[r] = 1.0f / sm[r];
        }
        #pragma unroll
        for (int t = 0; t < 32; t++)
            #pragma unroll
            for (int r = 0; r < 4; r++) acc[t][r] *= sm[r];
        // wsum scatter
        #pragma unroll
        for (int t = 0; t < 32; t++) {
            #pragma unroll
            for (int r = 0; r < 4; r++) {
                int ql = w * 16 + quad * 4 + r;
                int rm = rmb[ql * 516 + t * 16 + cl];
                atomicAdd(&wsum[ql * 101 + rm], acc[t][r]);
            }
        }
    }
    __syncthreads();

    // ---------------- P4: stage V^T [32 d][520 keys] ----------------
    #pragma unroll
    for (int it = 0; it < 8; it++) {
        int idx = it * 256 + tid;
        int key = idx >> 2, part = idx & 3;
        uint4 vv = *(const uint4*)&Vg[(size_t)(b * S_ + key) * DH + h * PH + part * 8];
        f16x8 vh = __builtin_bit_cast(f16x8, vv);
        #pragma unroll
        for (int j = 0; j < 8; j++)
            big.VT[(part * 8 + j) * 520 + key] = f2h_u((float)vh[j]) , (void)0;
    }
    __syncthreads();

    // ---------------- P5: PV + ctx_rel + write ----------------
    {
        floatx4 ctx[2] = {};
        #pragma unroll
        for (int c = 0; c < 16; c++) {
            // write P chunk (32 keys) to per-wave buffer, C-layout -> rows
            #pragma unroll
            for (int tt = 0; tt < 2; tt++) {
                #pragma unroll
                for (int r = 0; r < 4; r++)
                    Pb[w][c & 1][(quad * 4 + r) * 40 + tt * 16 + cl] =
                        f2h_u(acc[c * 2 + tt][r]);
            }
            f16x8 pa = *(const f16x8*)&Pb[w][c & 1][cl * 40 + quad * 8];
            #pragma unroll
            for (int nt = 0; nt < 2; nt++) {
                f16x8 vf = *(const f16x8*)&big.VT[(nt * 16 + cl) * 520 + c * 32 + quad * 8];
                ctx[nt] = __builtin_amdgcn_mfma_f32_16x16x32_f16(pa, vf, ctx[nt], 0, 0, 0);
            }
        }
        // ctx_rel = wsum @ rel_v
        for (int r = 0; r < NREL; r++) {
            float rv0 = relb[r * 36 + cl];
            float rv1 = relb[r * 36 + 16 + cl];
            #pragma unroll
            for (int rr = 0; rr < 4; rr++) {
                float ws = wsum[(w * 16 + quad * 4 + rr) * 101 + r];
                ctx[0][rr] += ws * rv0;
                ctx[1][rr] += ws * rv1;
            }
        }
        #pragma unroll
        for (int nt = 0; nt < 2; nt++) {
            #pragma unroll
            for (int rr = 0; rr < 4; rr++) {
                int row = b * S_ + q0 + w * 16 + quad * 4 + rr;
                int col = h * PH + nt * 16 + cl;
                CTX[(size_t)row * DH + col] = f2h_u(ctx[nt][rr]);
            }
        }
    }
}

// ---------------------------------------------------------------------------
extern "C" void kernel_launch(void* const* d_in, const int* in_sizes, int n_in,
                              void* d_out, int out_size, void* d_ws, size_t ws_size,
                              hipStream_t stream)
{
    const float* hidden = (const float*)d_in[0];
    const float* Wq = (const float*)d_in[1];  const float* bq = (const float*)d_in[2];
    const float* Wk = (const float*)d_in[3];  const float* bk = (const float*)d_in[4];
    const float* Wv = (const float*)d_in[5];  const float* bv = (const float*)d_in[6];
    const float* Wo = (const float*)d_in[7];  const float* bo = (const float*)d_in[8];
    const float* relk = (const float*)d_in[9];
    const float* relv = (const float*)d_in[10];
    const float* W1 = (const float*)d_in[11]; const float* b1 = (const float*)d_in[12];
    const float* W2 = (const float*)d_in[13]; const float* b2 = (const float*)d_in[14];
    const int*   RM = (const int*)d_in[15];
    float* out = (float*)d_out;

    const size_t SZ = (size_t)MROWS * DH;          // 3,276,800 elems
    const size_t SZB = SZ * 2;                     // f16 bytes

    char* ws = (char*)d_ws;
    unsigned short* hb   = (unsigned short*)(ws);              // hidden f16
    unsigned short* qf   = (unsigned short*)(ws + SZB);        // q f16
    unsigned short* kf   = (unsigned short*)(ws + 2*SZB);      // k f16
    unsigned short* vf   = (unsigned short*)(ws + 3*SZB);      // v f16
    unsigned short* ctxf = (unsigned short*)(ws + 4*SZB);      // ctx f16
    unsigned short* aof  = (unsigned short*)(ws + 5*SZB);      // attn_out f16
    unsigned short* hff  = (unsigned short*)(ws + 6*SZB);      // ffn hidden f16
    unsigned short* Wt   = (unsigned short*)(ws + 7*SZB);      // 6 x [N][K] f16
    const size_t WSZ = (size_t)DH * DH;
    unsigned short *Wtq = Wt,         *Wtk = Wt + WSZ,   *Wtv = Wt + 2*WSZ,
                   *Wto = Wt + 3*WSZ, *Wt1 = Wt + 4*WSZ, *Wt2 = Wt + 5*WSZ;

    fcast_k<<<dim3((SZ/4 + 255)/256), 256, 0, stream>>>(hidden, hb, (int)(SZ/4));
    wcast_k<<<dim3(DH/32, DH/32, 6), 256, 0, stream>>>(Wq, Wk, Wv, Wo, W1, W2, Wt);

    // QKV fused (A staged once per tile) — grid 25x16 = 400 blocks
    gemm_qkv3_k<<<dim3(DH/BN, MROWS/BM), 256, 0, stream>>>(
        hb, Wtq, Wtk, Wtv, bq, bk, bv, qf, kf, vf);

    attn_k<<<dim3(S_/64, NH, B_), 256, 0, stream>>>(qf, kf, vf, relk, relv, RM, ctxf);

    // attn_out = ctx @ Wo + bo
    gemm_f16_k<false, false, true><<<dim3(DH/BN, MROWS/BM, 1), 256, 0, stream>>>(
        ctxf, Wto, Wto, Wto, bo, bo, bo,
        nullptr, nullptr, nullptr, aof, aof, aof);

    // h = gelu(attn_out @ W1 + b1)
    gemm_f16_k<true, false, true><<<dim3(DH/BN, MROWS/BM, 1), 256, 0, stream>>>(
        aof, Wt1, Wt1, Wt1, b1, b1, b1,
        nullptr, nullptr, nullptr, hff, hff, hff);

    // out = h @ W2 + b2  (fp32 out)
    gemm_f16_k<false, true, false><<<dim3(DH/BN, MROWS/BM, 1), 256, 0, stream>>>(
        hff, Wt2, Wt2, Wt2, b2, b2, b2,
        out, out, out, nullptr, nullptr, nullptr);
}